// Round 7
// baseline (5385.846 us; speedup 1.0000x reference)
//
#include <hip/hip_runtime.h>
#include <math.h>

// ---------------------------------------------------------------------------
// Round 6 (resubmit after broker timeout): L2 locality + occupancy.
//  - Both GEMMs: A-panel-major grid (x = N-tile, y = M-tile) so the small B
//    stays L2-resident and each A-panel is fetched ~once.
//  - gemm_f32b: split-K via f32 atomic accumulation (2 parts, deterministic),
//    optional relu-on-A-load (W2 consumes W1's raw sums).
//  - mol QKV merged into one N=1536 split3 GEMM (row stride 1536).
// ---------------------------------------------------------------------------

#define DEV __device__ __forceinline__

constexpr int NN   = 8192;
constexpr int EE   = 32768;
constexpr int ENL  = EE + NN;
constexpr int D    = 512;
constexpr int RGS  = 512;
constexpr int RS   = 6;
constexpr int BMOL = 64;
constexpr int SEQS = 139;
constexpr int NSEQ = BMOL * SEQS;  // 8896
constexpr int MHAT = 8960;         // 70 tiles of 128
constexpr int DFF  = 2048;

typedef short bf8 __attribute__((ext_vector_type(8)));
typedef float f32x4 __attribute__((ext_vector_type(4)));
typedef _Float16 half2_t __attribute__((ext_vector_type(2)));
typedef _Float16 half8_t __attribute__((ext_vector_type(8)));

#ifdef __has_builtin
#if __has_builtin(__builtin_amdgcn_fdot2)
#define HAS_FDOT2 1
#endif
#endif
#ifndef HAS_FDOT2
#define HAS_FDOT2 0
#endif

DEV float wsum(float v) {
    for (int o = 32; o > 0; o >>= 1) v += __shfl_xor(v, o, 64);
    return v;
}
DEV float wmax(float v) {
    for (int o = 32; o > 0; o >>= 1) v = fmaxf(v, __shfl_xor(v, o, 64));
    return v;
}
DEV unsigned short f2bf(float x) {
    unsigned u = __float_as_uint(x);
    u += 0x7FFFu + ((u >> 16) & 1u);
    return (unsigned short)(u >> 16);
}
DEV float bf2f(unsigned short h) { return __uint_as_float((unsigned)h << 16); }

DEV float dot8(half8_t a, half8_t b, float acc) {
#if HAS_FDOT2
    acc = __builtin_amdgcn_fdot2(__builtin_shufflevector(a, a, 0, 1),
                                 __builtin_shufflevector(b, b, 0, 1), acc, false);
    acc = __builtin_amdgcn_fdot2(__builtin_shufflevector(a, a, 2, 3),
                                 __builtin_shufflevector(b, b, 2, 3), acc, false);
    acc = __builtin_amdgcn_fdot2(__builtin_shufflevector(a, a, 4, 5),
                                 __builtin_shufflevector(b, b, 4, 5), acc, false);
    acc = __builtin_amdgcn_fdot2(__builtin_shufflevector(a, a, 6, 7),
                                 __builtin_shufflevector(b, b, 6, 7), acc, false);
#else
#pragma unroll
    for (int i = 0; i < 8; ++i) acc += (float)a[i] * (float)b[i];
#endif
    return acc;
}

// ---------------------------------------------------------------------------
// Batched / split-K f32 GEMM. 128x128 tile, 8x8/thread.
// grid: (N/128, M/128, nb*kparts). flags: 1 bias(kp==0 only), 2 relu epi
// (kparts==1 only), 4 atomic accumulate into pre-zeroed C, 8 relu on A load.
// ---------------------------------------------------------------------------
struct GB {
    const float* A;
    const float* B0; const float* B1; const float* B2;
    const float* bias0; const float* bias1; const float* bias2;
    float* C0; float* C1; float* C2;
    int M, N, K, flags, kparts, ksz;
    long long cstride;   // partial-buffer stride (non-atomic splitK)
};

__global__ __launch_bounds__(256) void gemm_f32b(GB g) {
    __shared__ float As[16][132];
    __shared__ float Bs[16][128];
    const int z = blockIdx.z;
    const int bb = z / g.kparts, kp = z - bb * g.kparts;
    const float* B = bb == 0 ? g.B0 : (bb == 1 ? g.B1 : g.B2);
    const float* bias = bb == 0 ? g.bias0 : (bb == 1 ? g.bias1 : g.bias2);
    float* C = (bb == 0 ? g.C0 : (bb == 1 ? g.C1 : g.C2));
    if (!(g.flags & 4)) C += (size_t)kp * g.cstride;
    const int M = g.M, N = g.N;

    const int tid = threadIdx.x;
    const int wv = tid >> 6, ln = tid & 63;
    const int mg = ((ln >> 3) & 7) | ((wv & 1) << 3);
    const int ng = (ln & 7) | ((wv >> 1) << 3);
    const int m0 = blockIdx.y * 128, n0 = blockIdx.x * 128;

    const int a_row = tid >> 2;
    const int a_kg  = tid & 3;
    const int b_row = tid >> 5;
    const int b_cg  = tid & 31;

    float acc[8][8] = {};
    const int kbeg = kp * g.ksz, kend = kbeg + g.ksz;
    for (int k0 = kbeg; k0 < kend; k0 += 16) {
#pragma unroll
        for (int i = 0; i < 2; ++i) {
            int r = a_row + i * 64;
            int gr = m0 + r; if (gr >= M) gr = M - 1;
            float4 av = *(const float4*)&g.A[(size_t)gr * g.K + k0 + a_kg * 4];
            if (g.flags & 8) {
                av.x = fmaxf(av.x, 0.f); av.y = fmaxf(av.y, 0.f);
                av.z = fmaxf(av.z, 0.f); av.w = fmaxf(av.w, 0.f);
            }
            As[a_kg * 4 + 0][r] = av.x;
            As[a_kg * 4 + 1][r] = av.y;
            As[a_kg * 4 + 2][r] = av.z;
            As[a_kg * 4 + 3][r] = av.w;
        }
#pragma unroll
        for (int i = 0; i < 2; ++i) {
            int r = b_row + i * 8;
            float4 bv = *(const float4*)&B[(size_t)(k0 + r) * N + n0 + b_cg * 4];
            *(float4*)&Bs[r][b_cg * 4] = bv;
        }
        __syncthreads();
#pragma unroll
        for (int k = 0; k < 16; ++k) {
            float a0[8], b0[8];
            *(float4*)&a0[0] = *(const float4*)&As[k][mg * 8];
            *(float4*)&a0[4] = *(const float4*)&As[k][mg * 8 + 4];
            *(float4*)&b0[0] = *(const float4*)&Bs[k][ng * 8];
            *(float4*)&b0[4] = *(const float4*)&Bs[k][ng * 8 + 4];
#pragma unroll
            for (int i = 0; i < 8; ++i)
#pragma unroll
                for (int j = 0; j < 8; ++j) acc[i][j] += a0[i] * b0[j];
        }
        __syncthreads();
    }
#pragma unroll
    for (int i = 0; i < 8; ++i) {
        int gr = m0 + mg * 8 + i;
        if (gr >= M) break;
        float* cp = &C[(size_t)gr * N + n0 + ng * 8];
        float o[8];
#pragma unroll
        for (int j = 0; j < 8; ++j) o[j] = acc[i][j];
        if ((g.flags & 1) && kp == 0) {
            const float* bp = bias + n0 + ng * 8;
#pragma unroll
            for (int j = 0; j < 8; ++j) o[j] += bp[j];
        }
        if ((g.flags & 2) && g.kparts == 1) {
#pragma unroll
            for (int j = 0; j < 8; ++j) o[j] = fmaxf(o[j], 0.f);
        }
        if (g.flags & 4) {
#pragma unroll
            for (int j = 0; j < 8; ++j) atomicAdd(&cp[j], o[j]);
        } else {
            *(float4*)&cp[0] = make_float4(o[0], o[1], o[2], o[3]);
            *(float4*)&cp[4] = make_float4(o[4], o[5], o[6], o[7]);
        }
    }
}

// ---------------------------------------------------------------------------
// MFMA bf16x3-split GEMM (mol phase). A-panel-major grid (x = N-tile).
// ---------------------------------------------------------------------------
__global__ __launch_bounds__(256) void gemm_split3(
    const unsigned short* __restrict__ Ah, const unsigned short* __restrict__ Al,
    const unsigned short* __restrict__ Bh, const unsigned short* __restrict__ Bl,
    const float* __restrict__ bias, float* __restrict__ C,
    unsigned short* __restrict__ Ch, unsigned short* __restrict__ Cl,
    int N, int K, int flags)
{
    __shared__ unsigned short sA[2][128][40];
    __shared__ unsigned short sB[2][128][40];
    const int tid = threadIdx.x;
    const int wv = tid >> 6, lane = tid & 63;
    const int m0 = blockIdx.y * 128, n0 = blockIdx.x * 128;
    const int srow = tid >> 2, sc8 = (tid & 3) * 8;
    const int mw = (wv & 1) * 64, nw = (wv >> 1) * 64;
    const int fr = lane & 15, fq = lane >> 4;
    const int ko = fq * 8;

    f32x4 acc[4][4];
    f32x4 zero = {0.f, 0.f, 0.f, 0.f};
#pragma unroll
    for (int i = 0; i < 4; ++i)
#pragma unroll
        for (int j = 0; j < 4; ++j) acc[i][j] = zero;

    for (int k0 = 0; k0 < K; k0 += 32) {
#pragma unroll
        for (int h = 0; h < 2; ++h) {
            int r = srow + h * 64;
            *(bf8*)&sA[0][r][sc8] = *(const bf8*)&Ah[(size_t)(m0 + r) * K + k0 + sc8];
            *(bf8*)&sA[1][r][sc8] = *(const bf8*)&Al[(size_t)(m0 + r) * K + k0 + sc8];
            *(bf8*)&sB[0][r][sc8] = *(const bf8*)&Bh[(size_t)(n0 + r) * K + k0 + sc8];
            *(bf8*)&sB[1][r][sc8] = *(const bf8*)&Bl[(size_t)(n0 + r) * K + k0 + sc8];
        }
        __syncthreads();
        bf8 ah[4], al[4], bh[4], bl[4];
#pragma unroll
        for (int t = 0; t < 4; ++t) {
            ah[t] = *(const bf8*)&sA[0][mw + t * 16 + fr][ko];
            al[t] = *(const bf8*)&sA[1][mw + t * 16 + fr][ko];
            bh[t] = *(const bf8*)&sB[0][nw + t * 16 + fr][ko];
            bl[t] = *(const bf8*)&sB[1][nw + t * 16 + fr][ko];
        }
#pragma unroll
        for (int i = 0; i < 4; ++i)
#pragma unroll
            for (int j = 0; j < 4; ++j) {
                acc[i][j] = __builtin_amdgcn_mfma_f32_16x16x32_bf16(ah[i], bh[j], acc[i][j], 0, 0, 0);
                acc[i][j] = __builtin_amdgcn_mfma_f32_16x16x32_bf16(ah[i], bl[j], acc[i][j], 0, 0, 0);
                acc[i][j] = __builtin_amdgcn_mfma_f32_16x16x32_bf16(al[i], bh[j], acc[i][j], 0, 0, 0);
            }
        __syncthreads();
    }
#pragma unroll
    for (int i = 0; i < 4; ++i)
#pragma unroll
        for (int j = 0; j < 4; ++j) {
            int col = n0 + nw + j * 16 + fr;
#pragma unroll
            for (int r = 0; r < 4; ++r) {
                int row = m0 + mw + i * 16 + fq * 4 + r;
                float o = acc[i][j][r];
                if (flags & 1) o += bias[col];
                if (flags & 2) o = fmaxf(o, 0.f);
                size_t idx = (size_t)row * N + col;
                if (flags & 4) {
                    unsigned short hb_ = f2bf(o);
                    Ch[idx] = hb_;
                    Cl[idx] = f2bf(o - bf2f(hb_));
                } else {
                    C[idx] = o;
                }
            }
        }
}

__global__ void asplit4(const float* __restrict__ src, unsigned short* __restrict__ hh,
                        unsigned short* __restrict__ ll, int n4) {
    int i = blockIdx.x * 256 + threadIdx.x;
    if (i >= n4) return;
    float4 v = ((const float4*)src)[i];
    ushort4 h, l;
    h.x = f2bf(v.x); l.x = f2bf(v.x - bf2f(h.x));
    h.y = f2bf(v.y); l.y = f2bf(v.y - bf2f(h.y));
    h.z = f2bf(v.z); l.z = f2bf(v.z - bf2f(h.z));
    h.w = f2bf(v.w); l.w = f2bf(v.w - bf2f(h.w));
    ((ushort4*)hh)[i] = h;
    ((ushort4*)ll)[i] = l;
}

__global__ void wsplitT(const float* __restrict__ w, unsigned short* __restrict__ bh,
                        unsigned short* __restrict__ bl, int K, int N) {
    int i = blockIdx.x * 256 + threadIdx.x;
    if (i >= K * N) return;
    int k = i / N, n = i - k * N;
    float x = w[i];
    unsigned short h = f2bf(x);
    unsigned short l = f2bf(x - bf2f(h));
    bh[(size_t)n * K + k] = h;
    bl[(size_t)n * K + k] = l;
}

// ---------------------------------------------------------------------------
// Row LayerNorm (D=512), wave per row. flags: 1 relu, 2 LN. parts: sum
// split-K partials x[p][rows][D] before (res, bias, LN).
// ---------------------------------------------------------------------------
__global__ __launch_bounds__(256) void ln_rows(
    const float* __restrict__ x, const float* __restrict__ res,
    const float* __restrict__ bias, const float* __restrict__ g,
    const float* __restrict__ be, float* __restrict__ out, int rows, int flags,
    int parts)
{
    int r = blockIdx.x * 4 + (threadIdx.x >> 6);
    if (r >= rows) return;
    int lane = threadIdx.x & 63;
    size_t base = (size_t)r * D;
    size_t pstride = (size_t)rows * D;
    float v[8];
#pragma unroll
    for (int i = 0; i < 8; ++i) {
        int d = lane + i * 64;
        float t = x[base + d];
        for (int p = 1; p < parts; ++p) t += x[p * pstride + base + d];
        if (res)  t += res[base + d];
        if (bias) t += bias[d];
        v[i] = t;
    }
    if (flags & 2) {
        float s = 0;
#pragma unroll
        for (int i = 0; i < 8; ++i) s += v[i];
        float mu = wsum(s) * (1.f / 512.f);
        float q = 0;
#pragma unroll
        for (int i = 0; i < 8; ++i) { float d0 = v[i] - mu; q += d0 * d0; }
        float inv = rsqrtf(wsum(q) * (1.f / 512.f) + 1e-5f);
#pragma unroll
        for (int i = 0; i < 8; ++i) {
            int d = lane + i * 64;
            float o = (v[i] - mu) * inv * g[d] + be[d];
            if (flags & 1) o = fmaxf(o, 0.f);
            out[base + d] = o;
        }
    } else {
#pragma unroll
        for (int i = 0; i < 8; ++i) {
            int d = lane + i * 64;
            float o = v[i];
            if (flags & 1) o = fmaxf(o, 0.f);
            out[base + d] = o;
        }
    }
}

__global__ void fill_f32(float* p, float v, int n) {
    int i = blockIdx.x * 256 + threadIdx.x;
    if (i < n) p[i] = v;
}

// ---------------------------------------------------------------------------
// Graph preprocessing
// ---------------------------------------------------------------------------
__global__ void deg_int(const int* __restrict__ ei, int* __restrict__ degi) {
    int e = blockIdx.x * 256 + threadIdx.x;
    if (e >= EE) return;
    atomicAdd(&degi[ei[EE + e]], 1);
}

__global__ __launch_bounds__(256) void scan_deg(const int* __restrict__ degi,
                                                int* __restrict__ off) {
    __shared__ int ps[256];
    int tid = threadIdx.x;
    int base = tid * 32;
    int loc[32];
    int s = 0;
#pragma unroll
    for (int i = 0; i < 32; ++i) { loc[i] = s; s += degi[base + i]; }
    ps[tid] = s;
    __syncthreads();
    for (int o = 1; o < 256; o <<= 1) {
        int v = (tid >= o) ? ps[tid - o] : 0;
        __syncthreads();
        ps[tid] += v;
        __syncthreads();
    }
    int pre = (tid == 0) ? 0 : ps[tid - 1];
#pragma unroll
    for (int i = 0; i < 32; ++i) off[base + i] = pre + loc[i];
    if (tid == 255) off[8192] = ps[255];
}

__global__ void csr_fill(const int* __restrict__ ei, int* __restrict__ cnt,
                         const int* __restrict__ off, int* __restrict__ adj) {
    int e = blockIdx.x * 256 + threadIdx.x;
    if (e >= EE) return;
    int dn = ei[EE + e];
    int p = atomicAdd(&cnt[dn], 1);
    adj[off[dn] + p] = e;
}

__global__ void eagg_acc(const float* __restrict__ eattr, const int* __restrict__ ei,
                         float* __restrict__ agg) {
    int id = blockIdx.x * 256 + threadIdx.x;
    if (id >= EE * 16) return;
    int e = id >> 4, c = id & 15;
    atomicAdd(&agg[(size_t)ei[EE + e] * 16 + c], eattr[id]);
}

__global__ void ein_build(const float* __restrict__ eattr, const float* __restrict__ agg,
                          const int* __restrict__ degi, float* __restrict__ ein) {
    int r = blockIdx.x * 256 + threadIdx.x;
    if (r >= ENL) return;
    float* o = &ein[(size_t)r * 17];
    if (r < EE) {
        const float* a = &eattr[(size_t)r * 16];
#pragma unroll
        for (int k = 0; k < 16; ++k) o[k] = a[k];
        o[16] = 1.f;
    } else {
        int n = r - EE;
        int dg = degi[n];
        float inv = 1.f / (float)(dg > 1 ? dg : 1);
        const float* a = &agg[(size_t)n * 16];
#pragma unroll
        for (int k = 0; k < 16; ++k) o[k] = a[k] * inv;
        o[16] = dg > 0 ? 1.f : 0.f;
    }
}

__global__ __launch_bounds__(256) void we17_build(
    const float* __restrict__ epw, const float* __restrict__ epb,
    const float* __restrict__ we_all, float* __restrict__ we17_all) {
    int j = blockIdx.x * 256 + threadIdx.x;
    int kk = blockIdx.y, l = blockIdx.z;
    const float* we = we_all + (size_t)l * D * D;
    float* we17 = we17_all + (size_t)l * 17 * D;
    float acc[17];
#pragma unroll
    for (int i = 0; i < 17; ++i) acc[i] = 0.f;
    for (int k = kk * 128; k < kk * 128 + 128; ++k) {
        float wkj = we[(size_t)k * 512 + j];
#pragma unroll
        for (int i = 0; i < 16; ++i) acc[i] += epw[(size_t)i * 512 + k] * wkj;
        acc[16] += epb[k] * wkj;
    }
#pragma unroll
    for (int i = 0; i < 17; ++i) atomicAdd(&we17[(size_t)i * 512 + j], acc[i]);
}

// ---------------------------------------------------------------------------
// GATv2 per-node
// ---------------------------------------------------------------------------
__global__ __launch_bounds__(256) void gat_node(
    const float* __restrict__ xl, const float* __restrict__ xr,
    const float* __restrict__ ein, const float* __restrict__ we17,
    const int* __restrict__ off, const int* __restrict__ adj,
    const int* __restrict__ ei, const float* __restrict__ att,
    float* __restrict__ out)
{
    __shared__ float we[17][512];
    __shared__ float sc[4][88];
    int tid = threadIdx.x;
    for (int i = tid; i < 17 * 512; i += 256) we[i >> 9][i & 511] = we17[i];
    __syncthreads();
    int wv = tid >> 6, lane = tid & 63;
    int n = blockIdx.x * 4 + wv;
    float xr8[8], att8[8];
#pragma unroll
    for (int i = 0; i < 8; ++i) {
        int d = lane + i * 64;
        xr8[i] = xr[(size_t)n * D + d];
        att8[i] = att[d];
    }
    int o0 = off[n];
    int deg = off[n + 1] - o0;
    if (deg > 80) deg = 80;
    for (int j = 0; j <= deg; ++j) {
        int er, s;
        if (j < deg) { int e = adj[o0 + j]; er = e; s = ei[e]; }
        else         { er = EE + n; s = n; }
        const float* ep = &ein[(size_t)er * 17];
        float e17[17];
#pragma unroll
        for (int k = 0; k < 17; ++k) e17[k] = ep[k];
        float a = 0;
#pragma unroll
        for (int i = 0; i < 8; ++i) {
            int d = lane + i * 64;
            float m = xl[(size_t)s * D + d] + xr8[i];
#pragma unroll
            for (int k = 0; k < 17; ++k) m += e17[k] * we[k][d];
            m = m > 0.f ? m : 0.2f * m;
            a += att8[i] * m;
        }
        a = wsum(a);
        if (lane == 0) sc[wv][j] = a;
    }
    __syncthreads();
    float mx = -1e30f;
    for (int j = 0; j <= deg; ++j) mx = fmaxf(mx, sc[wv][j]);
    float z = 0;
    for (int j = 0; j <= deg; ++j) z += expf(sc[wv][j] - mx);
    float acc[8] = {};
    for (int j = 0; j <= deg; ++j) {
        int s = (j < deg) ? ei[adj[o0 + j]] : n;
        float w = expf(sc[wv][j] - mx);
#pragma unroll
        for (int i = 0; i < 8; ++i) acc[i] += w * xl[(size_t)s * D + lane + i * 64];
    }
    float inv = 1.f / z;
#pragma unroll
    for (int i = 0; i < 8; ++i) out[(size_t)n * D + lane + i * 64] = acc[i] * inv;
}

// ---------------------------------------------------------------------------
// Ring helpers
// ---------------------------------------------------------------------------
__global__ void gather_rows(const float* __restrict__ src, const int* __restrict__ idx,
                            float* __restrict__ dst, int nrows) {
    int i = blockIdx.x * 256 + threadIdx.x;
    int r = i >> 9;
    if (r >= nrows) return;
    dst[i] = src[(size_t)idx[r] * D + (i & 511)];
}

__global__ __launch_bounds__(256) void ring_attn(
    const float* __restrict__ q, const float* __restrict__ k,
    const float* __restrict__ v, float* __restrict__ o)
{
    int rh = blockIdx.x, r = rh >> 1, hh = rh & 1;
    __shared__ float qs[RS * 256], ks[RS * 256], vs[RS * 256];
    __shared__ float scs[36], pr[36];
    int tid = threadIdx.x;
    size_t base = (size_t)r * RS * D + hh * 256;
    for (int i = tid; i < RS * 256; i += 256) {
        int si = i >> 8, d = i & 255;
        size_t g = base + (size_t)si * D + d;
        qs[i] = q[g]; ks[i] = k[g]; vs[i] = v[g];
    }
    __syncthreads();
    if (tid < 36) {
        int i = tid / 6, j = tid % 6;
        float a = 0;
        for (int d = 0; d < 256; ++d) a += qs[i * 256 + d] * ks[j * 256 + d];
        scs[tid] = a * (1.f / 16.f);
    }
    __syncthreads();
    if (tid < 6) {
        float mx = -1e30f;
        for (int j = 0; j < 6; ++j) mx = fmaxf(mx, scs[tid * 6 + j]);
        float p[6], s = 0;
        for (int j = 0; j < 6; ++j) { p[j] = expf(scs[tid * 6 + j] - mx); s += p[j]; }
        for (int j = 0; j < 6; ++j) pr[tid * 6 + j] = p[j] / s;
    }
    __syncthreads();
    for (int i = tid; i < RS * 256; i += 256) {
        int si = i >> 8, d = i & 255;
        float a = 0;
        for (int j = 0; j < 6; ++j) a += pr[si * 6 + j] * vs[j * 256 + d];
        o[base + (size_t)si * D + d] = a;
    }
}

// ---------------------------------------------------------------------------
// mol_attn3: fused per-(b,h), row stride rs for q/k/v (merged QKV layout).
// ---------------------------------------------------------------------------
constexpr int ATT_K_H  = SEQS * 128;
constexpr int ATT_V_ROW = 152;
constexpr int ATT_V_H  = 128 * ATT_V_ROW;
constexpr int ATT_PS_ROW = 144;
constexpr int ATT_PS_H = 8 * ATT_PS_ROW;
constexpr int ATT_SMEM = (ATT_K_H + ATT_V_H + ATT_PS_H) * 2 + 8 * 64 * 4;  // 78848 B

__global__ __launch_bounds__(256) void mol_attn3(
    const float* __restrict__ q, const float* __restrict__ k,
    const float* __restrict__ v, float* __restrict__ o, int rs)
{
    extern __shared__ char smem[];
    _Float16* Ksh = (_Float16*)smem;
    _Float16* Vt  = Ksh + ATT_K_H;
    _Float16* ps  = Vt + ATT_V_H;
    half2_t*  qs  = (half2_t*)(ps + ATT_PS_H);
    const int tid = threadIdx.x, wv = tid >> 6, lane = tid & 63;
    const int b = blockIdx.x >> 2, hh = blockIdx.x & 3;
    const size_t hb = (size_t)b * SEQS * rs + hh * 128;
    const size_t ob = (size_t)b * SEQS * D + hh * 128;

    for (int i = tid; i < SEQS * 32; i += 256) {
        int j = i >> 5, d4 = i & 31;
        float4 kv = *(const float4*)&k[hb + (size_t)j * rs + d4 * 4];
        int off = j * 128 + (((d4 >> 1) ^ (j & 7)) << 3) + ((d4 & 1) << 2);
        *(half2_t*)(Ksh + off)     = half2_t{(_Float16)kv.x, (_Float16)kv.y};
        *(half2_t*)(Ksh + off + 2) = half2_t{(_Float16)kv.z, (_Float16)kv.w};
    }
    for (int i = tid; i < SEQS * 32; i += 256) {
        int j = i >> 5, d4 = i & 31;
        float4 vv = *(const float4*)&v[hb + (size_t)j * rs + d4 * 4];
        Vt[(d4 * 4 + 0) * ATT_V_ROW + j] = (_Float16)vv.x;
        Vt[(d4 * 4 + 1) * ATT_V_ROW + j] = (_Float16)vv.y;
        Vt[(d4 * 4 + 2) * ATT_V_ROW + j] = (_Float16)vv.z;
        Vt[(d4 * 4 + 3) * ATT_V_ROW + j] = (_Float16)vv.w;
    }
    for (int i = tid; i < 128 * 5; i += 256) {
        int d = i / 5, jt = SEQS + i % 5;
        Vt[d * ATT_V_ROW + jt] = (_Float16)0.f;
    }
    __syncthreads();

    const float scale = 0.08838834764831845f;
    for (int t = 0; t < 18; ++t) {
        int p = wv + 4 * t;
        if (p >= 70) continue;
        int q0 = 2 * p, q1 = 2 * p + 1;
        bool h1 = q1 < SEQS;
        {
            float2 f0 = *(const float2*)&q[hb + (size_t)q0 * rs + lane * 2];
            qs[(wv * 2 + 0) * 64 + lane] = half2_t{(_Float16)f0.x, (_Float16)f0.y};
            if (h1) {
                float2 f1 = *(const float2*)&q[hb + (size_t)q1 * rs + lane * 2];
                qs[(wv * 2 + 1) * 64 + lane] = half2_t{(_Float16)f1.x, (_Float16)f1.y};
            }
        }
        float s0[3], s1[3];
#pragma unroll
        for (int jj = 0; jj < 3; ++jj) { s0[jj] = -1e30f; s1[jj] = -1e30f; }
#pragma unroll
        for (int jj = 0; jj < 3; ++jj) {
            int j = lane + jj * 64;
            if (j < SEQS) {
                float a0 = 0, a1 = 0;
                const int jb = j * 128, jx = j & 7;
#pragma unroll
                for (int c = 0; c < 16; ++c) {
                    half8_t kk = *(const half8_t*)(Ksh + jb + ((c ^ jx) << 3));
                    half8_t q0v = *(const half8_t*)(qs + (wv * 2 + 0) * 64 + c * 4);
                    a0 = dot8(kk, q0v, a0);
                    if (h1) {
                        half8_t q1v = *(const half8_t*)(qs + (wv * 2 + 1) * 64 + c * 4);
                        a1 = dot8(kk, q1v, a1);
                    }
                }
                s0[jj] = a0 * scale; s1[jj] = a1 * scale;
            }
        }
        {
            float m0 = wmax(fmaxf(fmaxf(s0[0], s0[1]), s0[2]));
            float z0 = 0; float e0[3];
#pragma unroll
            for (int jj = 0; jj < 3; ++jj) {
                int j = lane + jj * 64;
                e0[jj] = (j < SEQS) ? expf(s0[jj] - m0) : 0.f;
                z0 += e0[jj];
            }
            z0 = wsum(z0); float inv0 = 1.f / z0;
#pragma unroll
            for (int jj = 0; jj < 3; ++jj) {
                int j = lane + jj * 64;
                if (j < ATT_PS_ROW) ps[(wv * 2 + 0) * ATT_PS_ROW + j] = (_Float16)(e0[jj] * inv0);
            }
        }
        if (h1) {
            float m1 = wmax(fmaxf(fmaxf(s1[0], s1[1]), s1[2]));
            float z1 = 0; float e1[3];
#pragma unroll
            for (int jj = 0; jj < 3; ++jj) {
                int j = lane + jj * 64;
                e1[jj] = (j < SEQS) ? expf(s1[jj] - m1) : 0.f;
                z1 += e1[jj];
            }
            z1 = wsum(z1); float inv1 = 1.f / z1;
#pragma unroll
            for (int jj = 0; jj < 3; ++jj) {
                int j = lane + jj * 64;
                if (j < ATT_PS_ROW) ps[(wv * 2 + 1) * ATT_PS_ROW + j] = (_Float16)(e1[jj] * inv1);
            }
        }
        float o00 = 0, o01 = 0, o10 = 0, o11 = 0;
#pragma unroll
        for (int c8 = 0; c8 < 18; ++c8) {
            half8_t va = *(const half8_t*)(Vt + lane * ATT_V_ROW + c8 * 8);
            half8_t vb = *(const half8_t*)(Vt + (lane + 64) * ATT_V_ROW + c8 * 8);
            half8_t p0 = *(const half8_t*)(ps + (wv * 2 + 0) * ATT_PS_ROW + c8 * 8);
            o00 = dot8(va, p0, o00);
            o01 = dot8(vb, p0, o01);
            if (h1) {
                half8_t p1 = *(const half8_t*)(ps + (wv * 2 + 1) * ATT_PS_ROW + c8 * 8);
                o10 = dot8(va, p1, o10);
                o11 = dot8(vb, p1, o11);
            }
        }
        o[ob + (size_t)q0 * D + lane]      = o00;
        o[ob + (size_t)q0 * D + lane + 64] = o01;
        if (h1) {
            o[ob + (size_t)q1 * D + lane]      = o10;
            o[ob + (size_t)q1 * D + lane + 64] = o11;
        }
    }
}

__global__ void ring_pick(const float* __restrict__ t, float* __restrict__ rv) {
    int i = blockIdx.x * 256 + threadIdx.x;
    if (i >= RGS * D) return;
    int r = i >> 9, d = i & 511;
    const float* p = &t[(size_t)r * RS * D + d];
    float best = p[0], ba = fabsf(best);
#pragma unroll
    for (int s = 1; s < RS; ++s) {
        float x = p[(size_t)s * D];
        float ax = fabsf(x);
        if (ax > ba) { ba = ax; best = x; }
    }
    rv[i] = best;
}

__global__ void assemble(const float* __restrict__ h, const float* __restrict__ rv,
                         const float* __restrict__ cls, const float* __restrict__ ringt,
                         const float* __restrict__ endt, float* __restrict__ seq) {
    int i = blockIdx.x * 256 + threadIdx.x;
    if (i >= NSEQ * D) return;
    int row = i >> 9, d = i & 511;
    int b = row / SEQS, p = row % SEQS;
    float val;
    if (p == 0)        val = cls[d];
    else if (p <= 128) val = h[((size_t)b * 128 + (p - 1)) * D + d];
    else if (p == 129) val = ringt[d];
    else if (p <= 137) val = rv[((size_t)b * 8 + (p - 130)) * D + d];
    else               val = endt[d];
    seq[i] = val;
}

// ---------------------------------------------------------------------------
extern "C" void kernel_launch(void* const* d_in, const int* in_sizes, int n_in,
                              void* d_out, int out_size, void* d_ws, size_t ws_size,
                              hipStream_t stream) {
    (void)in_sizes; (void)n_in; (void)out_size; (void)ws_size;

    const float* x          = (const float*)d_in[0];
    const float* edge_attr  = (const float*)d_in[1];
    const int*   ei         = (const int*)  d_in[2];
    const int*   rings_idx  = (const int*)  d_in[3];
    const float* x_proj_w   = (const float*)d_in[8];
    const float* x_proj_b   = (const float*)d_in[9];
    const float* e_proj_w   = (const float*)d_in[10];
    const float* e_proj_b   = (const float*)d_in[11];
    const float* gat_wl     = (const float*)d_in[12];
    const float* gat_bl     = (const float*)d_in[13];
    const float* gat_wr     = (const float*)d_in[14];
    const float* gat_br     = (const float*)d_in[15];
    const float* gat_we     = (const float*)d_in[16];
    const float* gat_att    = (const float*)d_in[17];
    const float* gat_bias   = (const float*)d_in[18];
    const float* gat_ln     = (const float*)d_in[19];
    const float* ring_attn_w= (const float*)d_in[20];
    const float* ring_attn_b= (const float*)d_in[21];
    const float* ring_w1    = (const float*)d_in[22];
    const float* ring_b1    = (const float*)d_in[23];
    const float* ring_w2    = (const float*)d_in[24];
    const float* ring_b2    = (const float*)d_in[25];
    const float* ring_ln    = (const float*)d_in[26];
    const float* mol_attn_w = (const float*)d_in[27];
    const float* mol_attn_b = (const float*)d_in[28];
    const float* mol_w1     = (const float*)d_in[29];
    const float* mol_b1     = (const float*)d_in[30];
    const float* mol_w2     = (const float*)d_in[31];
    const float* mol_b2     = (const float*)d_in[32];
    const float* mol_ln     = (const float*)d_in[33];
    const float* cls_tok    = (const float*)d_in[34];
    const float* ring_tok   = (const float*)d_in[35];
    const float* end_tok    = (const float*)d_in[36];

    constexpr size_t MB = 1024 * 1024;
    char* wsb = (char*)d_ws;
#define WSF(off) ((float*)(wsb + (size_t)(off)))
#define WSI(off) ((int*)(wsb + (size_t)(off)))
#define WSU(off) ((unsigned short*)(wsb + (size_t)(off)))

    // ---- GAT phase ----
    float* H    = WSF(0);
    float* XL   = WSF(16 * MB);
    float* XR   = WSF(32 * MB);
    float* HN   = WSF(48 * MB);
    float* EIN  = WSF(64 * MB);
    float* WE17 = WSF(67 * MB);
    float* AGG  = WSF(68 * MB);
    int*   DEGI = WSI(68 * MB + 512 * 1024);
    int*   OFF  = WSI(68 * MB + 576 * 1024);
    int*   CNT  = WSI(68 * MB + 640 * 1024);
    int*   ADJ  = WSI(68 * MB + 704 * 1024);
    float* RVEC = WSF(70 * MB);

    // ---- ring phase ----
    float* T    = WSF(71 * MB);
    float* RQ   = WSF(77 * MB);
    float* RK   = WSF(83 * MB);
    float* RV   = WSF(89 * MB);
    float* RO   = WSF(95 * MB);
    float* OP   = WSF(101 * MB);          // [2][3072][512] O partials
    float* RY   = WSF(113 * MB);
    float* RFF  = WSF(119 * MB);          // [3072][2048]
    float* W2P  = WSF(143 * MB);          // [4][3072][512] W2 partials
    float* RT2  = WSF(167 * MB);

    // ---- mol phase ----
    float* SEQ  = WSF(71 * MB);
    float* MQKV = WSF(89 * MB);           // [8960][1536] f32 = 52.5MB
    float* MO   = WSF(142 * MB);          // [8960][512]
    unsigned short* ACTh = WSU(161 * MB);
    unsigned short* ACTl = WSU(170 * MB);
    unsigned short* WQKVh = WSU(179 * MB);  // [1536][512]
    unsigned short* WQKVl = WSU(181 * MB);
    unsigned short* WOh  = WSU(183 * MB);
    unsigned short* WOl  = WSU(183 * MB + 512 * 1024);
    unsigned short* W1h  = WSU(184 * MB);
    unsigned short* W1l  = WSU(186 * MB);
    unsigned short* W2h  = WSU(188 * MB);
    unsigned short* W2l  = WSU(190 * MB);
    float* MTMP = WSF(89 * MB);           // over MQKV (dead after attn)
    float* MY   = WSF(107 * MB);
    unsigned short* MFFh = WSU(125 * MB); // [8960][2048] over MQKV tail + MO
    unsigned short* MFFl = WSU(16 * MB);  // over XL/XR/HN (dead)
    float* MT2  = WSF(71 * MB);           // over SEQ (dead)

    dim3 blk(256);

    // ---- phase 0: preprocessing ----
    hipMemsetAsync(DEGI, 0, NN * 4, stream);
    hipMemsetAsync(CNT, 0, NN * 4, stream);
    hipMemsetAsync(AGG, 0, (size_t)NN * 16 * 4, stream);
    hipMemsetAsync(WE17, 0, (size_t)6 * 17 * D * 4, stream);
    deg_int<<<EE / 256, blk, 0, stream>>>(ei, DEGI);
    scan_deg<<<1, blk, 0, stream>>>(DEGI, OFF);
    csr_fill<<<EE / 256, blk, 0, stream>>>(ei, CNT, OFF, ADJ);
    eagg_acc<<<EE * 16 / 256, blk, 0, stream>>>(edge_attr, ei, AGG);
    ein_build<<<ENL / 256, blk, 0, stream>>>(edge_attr, AGG, DEGI, EIN);
    we17_build<<<dim3(2, 4, 6), blk, 0, stream>>>(e_proj_w, e_proj_b, gat_we, WE17);

    // ---- phase 1: x projection (K=64, no split) ----
    {
        GB g{x, x_proj_w, nullptr, nullptr, x_proj_b, nullptr, nullptr,
             H, nullptr, nullptr, NN, D, 64, 1, 1, 64, 0};
        gemm_f32b<<<dim3(D / 128, NN / 128, 1), blk, 0, stream>>>(g);
    }

    // ---- phase 2: 6x GATv2 (f32; XL/XR via 2-way atomic split-K) ----
    for (int l = 0; l < 6; ++l) {
        hipMemsetAsync(XL, 0, (size_t)NN * D * 4, stream);
        hipMemsetAsync(XR, 0, (size_t)NN * D * 4, stream);
        GB g{H, gat_wl + (size_t)l * D * D, gat_wr + (size_t)l * D * D, nullptr,
             gat_bl + l * D, gat_br + l * D, nullptr,
             XL, XR, nullptr, NN, D, D, 1 | 4, 2, 256, 0};
        gemm_f32b<<<dim3(D / 128, NN / 128, 4), blk, 0, stream>>>(g);
        gat_node<<<NN / 4, blk, 0, stream>>>(XL, XR, EIN, WE17 + (size_t)l * 17 * D,
                                             OFF, ADJ, ei, gat_att + l * D, HN);
        if (l < 5) {
            ln_rows<<<NN / 4, blk, 0, stream>>>(HN, nullptr, gat_bias + l * D,
                gat_ln + (size_t)l * 2 * D, gat_ln + (size_t)l * 2 * D + D, H, NN, 3, 1);
        } else {
            ln_rows<<<NN / 4, blk, 0, stream>>>(HN, nullptr, gat_bias + l * D,
                nullptr, nullptr, H, NN, 0, 1);
        }
    }

    // ---- phase 3: ring encoder (f32) ----
    const int RROWS = RGS * RS;  // 3072
    gather_rows<<<RROWS * D / 256, blk, 0, stream>>>(H, rings_idx, T, RROWS);
    hipMemsetAsync(RQ, 0, (size_t)3 * RROWS * D * 4, stream);  // RQ,RK,RV contiguous
    {   // QKV batched z=3, kparts=2, atomic
        GB g{T, ring_attn_w + 0 * D * D, ring_attn_w + 1 * D * D, ring_attn_w + 2 * D * D,
             ring_attn_b + 0 * D, ring_attn_b + 1 * D, ring_attn_b + 2 * D,
             RQ, RK, RV, RROWS, D, D, 1 | 4, 2, 256, 0};
        gemm_f32b<<<dim3(D / 128, RROWS / 128, 6), blk, 0, stream>>>(g);
    }
    ring_attn<<<RGS * 2, blk, 0, stream>>>(RQ, RK, RV, RO);
    {   // O projection: 2-part partials, bias folded in ln
        GB g{RO, ring_attn_w + 3 * D * D, nullptr, nullptr, nullptr, nullptr, nullptr,
             OP, nullptr, nullptr, RROWS, D, D, 0, 2, 256, (long long)RROWS * D};
        gemm_f32b<<<dim3(D / 128, RROWS / 128, 2), blk, 0, stream>>>(g);
    }
    ln_rows<<<RROWS / 4, blk, 0, stream>>>(OP, T, ring_attn_b + 3 * D,
                                           ring_ln, ring_ln + D, RY, RROWS, 2, 2);
    hipMemsetAsync(RFF, 0, (size_t)RROWS * DFF * 4, stream);
    {   // W1: kparts=2 atomic, bias on kp0; relu deferred to W2 A-load
        GB g{RY, ring_w1, nullptr, nullptr, ring_b1, nullptr, nullptr,
             RFF, nullptr, nullptr, RROWS, DFF, D, 1 | 4, 2, 256, 0};
        gemm_f32b<<<dim3(DFF / 128, RROWS / 128, 2), blk, 0, stream>>>(g);
    }
    {   // W2: relu-on-A-load, 4-part partials
        GB g{RFF, ring_w2, nullptr, nullptr, nullptr, nullptr, nullptr,
             W2P, nullptr, nullptr, RROWS, D, DFF, 8, 4, 512, (long long)RROWS * D};
        gemm_f32b<<<dim3(D / 128, RROWS / 128, 4), blk, 0, stream>>>(g);
    }
    ln_rows<<<RROWS / 4, blk, 0, stream>>>(W2P, RY, ring_b2,
                                           ring_ln + 2 * D, ring_ln + 3 * D, RT2, RROWS, 2, 4);
    ring_pick<<<RGS * D / 256, blk, 0, stream>>>(RT2, RVEC);

    // ---- phase 4: mol encoder (MFMA bf16x3 + fused f16 attention) ----
    assemble<<<(NSEQ * D) / 256, blk, 0, stream>>>(H, RVEC, cls_tok, ring_tok, end_tok, SEQ);
    for (int z = 0; z < 3; ++z)
        wsplitT<<<(D * D + 255) / 256, blk, 0, stream>>>(
            mol_attn_w + (size_t)z * D * D, WQKVh + (size_t)z * D * D, WQKVl + (size_t)z * D * D, D, D);
    wsplitT<<<(D * D + 255) / 256, blk, 0, stream>>>(mol_attn_w + 3 * (size_t)D * D, WOh, WOl, D, D);
    wsplitT<<<(D * DFF + 255) / 256, blk, 0, stream>>>(mol_w1, W1h, W1l, D, DFF);
    wsplitT<<<(DFF * D + 255) / 256, blk, 0, stream>>>(mol_w2, W2h, W2l, DFF, D);

    const int N4_512 = MHAT * D / 4;
    float* MQ = MQKV;
    float* MK = MQKV + 512;
    float* MV = MQKV + 1024;
    asplit4<<<(N4_512 + 255) / 256, blk, 0, stream>>>(SEQ, ACTh, ACTl, N4_512);
    // merged QKV: N = 1536 (bias rows 0..2 of mol_attn_b are contiguous)
    gemm_split3<<<dim3(1536 / 128, MHAT / 128), blk, 0, stream>>>(
        ACTh, ACTl, WQKVh, WQKVl, mol_attn_b, MQKV, nullptr, nullptr, 1536, D, 1);

    hipFuncSetAttribute(reinterpret_cast<const void*>(mol_attn3),
                        hipFuncAttributeMaxDynamicSharedMemorySize, ATT_SMEM);
    mol_attn3<<<BMOL * 4, blk, ATT_SMEM, stream>>>(MQ, MK, MV, MO, 1536);

    asplit4<<<(N4_512 + 255) / 256, blk, 0, stream>>>(MO, ACTh, ACTl, N4_512);
    gemm_split3<<<dim3(D / 128, MHAT / 128), blk, 0, stream>>>(
        ACTh, ACTl, WOh, WOl, mol_attn_b + 3 * D, MTMP, nullptr, nullptr, D, D, 1);
    ln_rows<<<(NSEQ + 3) / 4, blk, 0, stream>>>(MTMP, SEQ, nullptr,
                                                mol_ln, mol_ln + D, MY, NSEQ, 2, 1);
    asplit4<<<(N4_512 + 255) / 256, blk, 0, stream>>>(MY, ACTh, ACTl, N4_512);
    gemm_split3<<<dim3(DFF / 128, MHAT / 128), blk, 0, stream>>>(
        ACTh, ACTl, W1h, W1l, mol_b1, nullptr, MFFh, MFFl, DFF, D, 1 | 2 | 4);
    gemm_split3<<<dim3(D / 128, MHAT / 128), blk, 0, stream>>>(
        MFFh, MFFl, W2h, W2l, mol_b2, MT2, nullptr, nullptr, D, DFF, 1);

    float* outf = (float*)d_out;
    ln_rows<<<(NSEQ + 3) / 4, blk, 0, stream>>>(MT2, MY, nullptr,
                                                mol_ln + 2 * D, mol_ln + 3 * D, outf, NSEQ, 2, 1);
    fill_f32<<<(BMOL * 128 + BMOL * 8 + 255) / 256, blk, 0, stream>>>(
        outf + (size_t)NSEQ * D, 1.0f, BMOL * 128 + BMOL * 8);
}

// Round 9
// 2260.748 us; speedup vs baseline: 2.3823x; 2.3823x over previous
//
#include <hip/hip_runtime.h>
#include <math.h>

// ---------------------------------------------------------------------------
// Round 8 (resubmit after container failure): revert atomic split-K (Round-7
// regression: 524MB atomic write amplification). f32 GEMM tile 128Mx64N ->
// 2x blocks (4/CU) for occupancy. Keep: A-panel-major grids (fixed split3
// over-fetch), merged QKV, mol_attn3, partial-buffer split-K (O, W2) folded
// exactly in ln_rows.
// ---------------------------------------------------------------------------

#define DEV __device__ __forceinline__

constexpr int NN   = 8192;
constexpr int EE   = 32768;
constexpr int ENL  = EE + NN;
constexpr int D    = 512;
constexpr int RGS  = 512;
constexpr int RS   = 6;
constexpr int BMOL = 64;
constexpr int SEQS = 139;
constexpr int NSEQ = BMOL * SEQS;  // 8896
constexpr int MHAT = 8960;         // 70 tiles of 128
constexpr int DFF  = 2048;

typedef short bf8 __attribute__((ext_vector_type(8)));
typedef float f32x4 __attribute__((ext_vector_type(4)));
typedef _Float16 half2_t __attribute__((ext_vector_type(2)));
typedef _Float16 half8_t __attribute__((ext_vector_type(8)));

#ifdef __has_builtin
#if __has_builtin(__builtin_amdgcn_fdot2)
#define HAS_FDOT2 1
#endif
#endif
#ifndef HAS_FDOT2
#define HAS_FDOT2 0
#endif

DEV float wsum(float v) {
    for (int o = 32; o > 0; o >>= 1) v += __shfl_xor(v, o, 64);
    return v;
}
DEV float wmax(float v) {
    for (int o = 32; o > 0; o >>= 1) v = fmaxf(v, __shfl_xor(v, o, 64));
    return v;
}
DEV unsigned short f2bf(float x) {
    unsigned u = __float_as_uint(x);
    u += 0x7FFFu + ((u >> 16) & 1u);
    return (unsigned short)(u >> 16);
}
DEV float bf2f(unsigned short h) { return __uint_as_float((unsigned)h << 16); }

DEV float dot8(half8_t a, half8_t b, float acc) {
#if HAS_FDOT2
    acc = __builtin_amdgcn_fdot2(__builtin_shufflevector(a, a, 0, 1),
                                 __builtin_shufflevector(b, b, 0, 1), acc, false);
    acc = __builtin_amdgcn_fdot2(__builtin_shufflevector(a, a, 2, 3),
                                 __builtin_shufflevector(b, b, 2, 3), acc, false);
    acc = __builtin_amdgcn_fdot2(__builtin_shufflevector(a, a, 4, 5),
                                 __builtin_shufflevector(b, b, 4, 5), acc, false);
    acc = __builtin_amdgcn_fdot2(__builtin_shufflevector(a, a, 6, 7),
                                 __builtin_shufflevector(b, b, 6, 7), acc, false);
#else
#pragma unroll
    for (int i = 0; i < 8; ++i) acc += (float)a[i] * (float)b[i];
#endif
    return acc;
}

// ---------------------------------------------------------------------------
// Batched / split-K f32 GEMM. 128Mx64N tile, 256 thr, 8x4/thread.
// grid: (N/64, M/128, nb*kparts). flags: 1 bias (kp==0), 2 relu (kparts==1).
// split-K writes partials at C + kp*cstride (folded downstream in ln_rows).
// ---------------------------------------------------------------------------
struct GB {
    const float* A;
    const float* B0; const float* B1; const float* B2;
    const float* bias0; const float* bias1; const float* bias2;
    float* C0; float* C1; float* C2;
    int M, N, K, flags, kparts, ksz;
    long long cstride;
};

__global__ __launch_bounds__(256) void gemm_f32b(GB g) {
    __shared__ float As[16][132];
    __shared__ float Bs[16][64];
    const int z = blockIdx.z;
    const int bb = z / g.kparts, kp = z - bb * g.kparts;
    const float* B = bb == 0 ? g.B0 : (bb == 1 ? g.B1 : g.B2);
    const float* bias = bb == 0 ? g.bias0 : (bb == 1 ? g.bias1 : g.bias2);
    float* C = (bb == 0 ? g.C0 : (bb == 1 ? g.C1 : g.C2)) + (size_t)kp * g.cstride;
    const int M = g.M, N = g.N;

    const int tid = threadIdx.x;
    const int tx = tid & 15, ty = tid >> 4;
    const int m0 = blockIdx.y * 128, n0 = blockIdx.x * 64;

    const int a_row = tid >> 2;          // 0..63 (+64)
    const int a_kc  = (tid & 3) * 4;
    const int b_row = tid >> 4;          // 0..15
    const int b_cg  = (tid & 15) * 4;

    float acc[8][4] = {};
    const int kbeg = kp * g.ksz, kend = kbeg + g.ksz;
    for (int k0 = kbeg; k0 < kend; k0 += 16) {
#pragma unroll
        for (int i = 0; i < 2; ++i) {
            int r = a_row + i * 64;
            int gr = m0 + r; if (gr >= M) gr = M - 1;
            float4 av = *(const float4*)&g.A[(size_t)gr * g.K + k0 + a_kc];
            As[a_kc + 0][r] = av.x;
            As[a_kc + 1][r] = av.y;
            As[a_kc + 2][r] = av.z;
            As[a_kc + 3][r] = av.w;
        }
        *(float4*)&Bs[b_row][b_cg] =
            *(const float4*)&B[(size_t)(k0 + b_row) * N + n0 + b_cg];
        __syncthreads();
#pragma unroll
        for (int k = 0; k < 16; ++k) {
            float a0[8], b0[4];
            *(float4*)&a0[0] = *(const float4*)&As[k][ty * 8];
            *(float4*)&a0[4] = *(const float4*)&As[k][ty * 8 + 4];
            *(float4*)&b0[0] = *(const float4*)&Bs[k][tx * 4];
#pragma unroll
            for (int i = 0; i < 8; ++i)
#pragma unroll
                for (int j = 0; j < 4; ++j) acc[i][j] += a0[i] * b0[j];
        }
        __syncthreads();
    }
#pragma unroll
    for (int i = 0; i < 8; ++i) {
        int gr = m0 + ty * 8 + i;
        if (gr >= M) break;
        float o0[4];
#pragma unroll
        for (int j = 0; j < 4; ++j) o0[j] = acc[i][j];
        if ((g.flags & 1) && kp == 0) {
            const float* bp = bias + n0 + tx * 4;
#pragma unroll
            for (int j = 0; j < 4; ++j) o0[j] += bp[j];
        }
        if ((g.flags & 2) && g.kparts == 1) {
#pragma unroll
            for (int j = 0; j < 4; ++j) o0[j] = fmaxf(o0[j], 0.f);
        }
        *(float4*)&C[(size_t)gr * N + n0 + tx * 4] =
            make_float4(o0[0], o0[1], o0[2], o0[3]);
    }
}

// ---------------------------------------------------------------------------
// MFMA bf16x3-split GEMM (mol phase). A-panel-major grid (x = N-tile).
// ---------------------------------------------------------------------------
__global__ __launch_bounds__(256) void gemm_split3(
    const unsigned short* __restrict__ Ah, const unsigned short* __restrict__ Al,
    const unsigned short* __restrict__ Bh, const unsigned short* __restrict__ Bl,
    const float* __restrict__ bias, float* __restrict__ C,
    unsigned short* __restrict__ Ch, unsigned short* __restrict__ Cl,
    int N, int K, int flags)
{
    __shared__ unsigned short sA[2][128][40];
    __shared__ unsigned short sB[2][128][40];
    const int tid = threadIdx.x;
    const int wv = tid >> 6, lane = tid & 63;
    const int m0 = blockIdx.y * 128, n0 = blockIdx.x * 128;
    const int srow = tid >> 2, sc8 = (tid & 3) * 8;
    const int mw = (wv & 1) * 64, nw = (wv >> 1) * 64;
    const int fr = lane & 15, fq = lane >> 4;
    const int ko = fq * 8;

    f32x4 acc[4][4];
    f32x4 zero = {0.f, 0.f, 0.f, 0.f};
#pragma unroll
    for (int i = 0; i < 4; ++i)
#pragma unroll
        for (int j = 0; j < 4; ++j) acc[i][j] = zero;

    for (int k0 = 0; k0 < K; k0 += 32) {
#pragma unroll
        for (int h = 0; h < 2; ++h) {
            int r = srow + h * 64;
            *(bf8*)&sA[0][r][sc8] = *(const bf8*)&Ah[(size_t)(m0 + r) * K + k0 + sc8];
            *(bf8*)&sA[1][r][sc8] = *(const bf8*)&Al[(size_t)(m0 + r) * K + k0 + sc8];
            *(bf8*)&sB[0][r][sc8] = *(const bf8*)&Bh[(size_t)(n0 + r) * K + k0 + sc8];
            *(bf8*)&sB[1][r][sc8] = *(const bf8*)&Bl[(size_t)(n0 + r) * K + k0 + sc8];
        }
        __syncthreads();
        bf8 ah[4], al[4], bh[4], bl[4];
#pragma unroll
        for (int t = 0; t < 4; ++t) {
            ah[t] = *(const bf8*)&sA[0][mw + t * 16 + fr][ko];
            al[t] = *(const bf8*)&sA[1][mw + t * 16 + fr][ko];
            bh[t] = *(const bf8*)&sB[0][nw + t * 16 + fr][ko];
            bl[t] = *(const bf8*)&sB[1][nw + t * 16 + fr][ko];
        }
#pragma unroll
        for (int i = 0; i < 4; ++i)
#pragma unroll
            for (int j = 0; j < 4; ++j) {
                acc[i][j] = __builtin_amdgcn_mfma_f32_16x16x32_bf16(ah[i], bh[j], acc[i][j], 0, 0, 0);
                acc[i][j] = __builtin_amdgcn_mfma_f32_16x16x32_bf16(ah[i], bl[j], acc[i][j], 0, 0, 0);
                acc[i][j] = __builtin_amdgcn_mfma_f32_16x16x32_bf16(al[i], bh[j], acc[i][j], 0, 0, 0);
            }
        __syncthreads();
    }
#pragma unroll
    for (int i = 0; i < 4; ++i)
#pragma unroll
        for (int j = 0; j < 4; ++j) {
            int col = n0 + nw + j * 16 + fr;
#pragma unroll
            for (int r = 0; r < 4; ++r) {
                int row = m0 + mw + i * 16 + fq * 4 + r;
                float o = acc[i][j][r];
                if (flags & 1) o += bias[col];
                if (flags & 2) o = fmaxf(o, 0.f);
                size_t idx = (size_t)row * N + col;
                if (flags & 4) {
                    unsigned short hb_ = f2bf(o);
                    Ch[idx] = hb_;
                    Cl[idx] = f2bf(o - bf2f(hb_));
                } else {
                    C[idx] = o;
                }
            }
        }
}

__global__ void asplit4(const float* __restrict__ src, unsigned short* __restrict__ hh,
                        unsigned short* __restrict__ ll, int n4) {
    int i = blockIdx.x * 256 + threadIdx.x;
    if (i >= n4) return;
    float4 v = ((const float4*)src)[i];
    ushort4 h, l;
    h.x = f2bf(v.x); l.x = f2bf(v.x - bf2f(h.x));
    h.y = f2bf(v.y); l.y = f2bf(v.y - bf2f(h.y));
    h.z = f2bf(v.z); l.z = f2bf(v.z - bf2f(h.z));
    h.w = f2bf(v.w); l.w = f2bf(v.w - bf2f(h.w));
    ((ushort4*)hh)[i] = h;
    ((ushort4*)ll)[i] = l;
}

__global__ void wsplitT(const float* __restrict__ w, unsigned short* __restrict__ bh,
                        unsigned short* __restrict__ bl, int K, int N) {
    int i = blockIdx.x * 256 + threadIdx.x;
    if (i >= K * N) return;
    int k = i / N, n = i - k * N;
    float x = w[i];
    unsigned short h = f2bf(x);
    unsigned short l = f2bf(x - bf2f(h));
    bh[(size_t)n * K + k] = h;
    bl[(size_t)n * K + k] = l;
}

// ---------------------------------------------------------------------------
// Row LayerNorm (D=512), wave per row. flags: 1 relu, 2 LN. parts: sum
// split-K partials x[p][rows][D] before (res, bias, LN).
// ---------------------------------------------------------------------------
__global__ __launch_bounds__(256) void ln_rows(
    const float* __restrict__ x, const float* __restrict__ res,
    const float* __restrict__ bias, const float* __restrict__ g,
    const float* __restrict__ be, float* __restrict__ out, int rows, int flags,
    int parts)
{
    int r = blockIdx.x * 4 + (threadIdx.x >> 6);
    if (r >= rows) return;
    int lane = threadIdx.x & 63;
    size_t base = (size_t)r * D;
    size_t pstride = (size_t)rows * D;
    float v[8];
#pragma unroll
    for (int i = 0; i < 8; ++i) {
        int d = lane + i * 64;
        float t = x[base + d];
        for (int p = 1; p < parts; ++p) t += x[p * pstride + base + d];
        if (res)  t += res[base + d];
        if (bias) t += bias[d];
        v[i] = t;
    }
    if (flags & 2) {
        float s = 0;
#pragma unroll
        for (int i = 0; i < 8; ++i) s += v[i];
        float mu = wsum(s) * (1.f / 512.f);
        float q = 0;
#pragma unroll
        for (int i = 0; i < 8; ++i) { float d0 = v[i] - mu; q += d0 * d0; }
        float inv = rsqrtf(wsum(q) * (1.f / 512.f) + 1e-5f);
#pragma unroll
        for (int i = 0; i < 8; ++i) {
            int d = lane + i * 64;
            float o = (v[i] - mu) * inv * g[d] + be[d];
            if (flags & 1) o = fmaxf(o, 0.f);
            out[base + d] = o;
        }
    } else {
#pragma unroll
        for (int i = 0; i < 8; ++i) {
            int d = lane + i * 64;
            float o = v[i];
            if (flags & 1) o = fmaxf(o, 0.f);
            out[base + d] = o;
        }
    }
}

__global__ void fill_f32(float* p, float v, int n) {
    int i = blockIdx.x * 256 + threadIdx.x;
    if (i < n) p[i] = v;
}

// ---------------------------------------------------------------------------
// Graph preprocessing
// ---------------------------------------------------------------------------
__global__ void deg_int(const int* __restrict__ ei, int* __restrict__ degi) {
    int e = blockIdx.x * 256 + threadIdx.x;
    if (e >= EE) return;
    atomicAdd(&degi[ei[EE + e]], 1);
}

__global__ __launch_bounds__(256) void scan_deg(const int* __restrict__ degi,
                                                int* __restrict__ off) {
    __shared__ int ps[256];
    int tid = threadIdx.x;
    int base = tid * 32;
    int loc[32];
    int s = 0;
#pragma unroll
    for (int i = 0; i < 32; ++i) { loc[i] = s; s += degi[base + i]; }
    ps[tid] = s;
    __syncthreads();
    for (int o = 1; o < 256; o <<= 1) {
        int v = (tid >= o) ? ps[tid - o] : 0;
        __syncthreads();
        ps[tid] += v;
        __syncthreads();
    }
    int pre = (tid == 0) ? 0 : ps[tid - 1];
#pragma unroll
    for (int i = 0; i < 32; ++i) off[base + i] = pre + loc[i];
    if (tid == 255) off[8192] = ps[255];
}

__global__ void csr_fill(const int* __restrict__ ei, int* __restrict__ cnt,
                         const int* __restrict__ off, int* __restrict__ adj) {
    int e = blockIdx.x * 256 + threadIdx.x;
    if (e >= EE) return;
    int dn = ei[EE + e];
    int p = atomicAdd(&cnt[dn], 1);
    adj[off[dn] + p] = e;
}

__global__ void eagg_acc(const float* __restrict__ eattr, const int* __restrict__ ei,
                         float* __restrict__ agg) {
    int id = blockIdx.x * 256 + threadIdx.x;
    if (id >= EE * 16) return;
    int e = id >> 4, c = id & 15;
    atomicAdd(&agg[(size_t)ei[EE + e] * 16 + c], eattr[id]);
}

__global__ void ein_build(const float* __restrict__ eattr, const float* __restrict__ agg,
                          const int* __restrict__ degi, float* __restrict__ ein) {
    int r = blockIdx.x * 256 + threadIdx.x;
    if (r >= ENL) return;
    float* o = &ein[(size_t)r * 17];
    if (r < EE) {
        const float* a = &eattr[(size_t)r * 16];
#pragma unroll
        for (int k = 0; k < 16; ++k) o[k] = a[k];
        o[16] = 1.f;
    } else {
        int n = r - EE;
        int dg = degi[n];
        float inv = 1.f / (float)(dg > 1 ? dg : 1);
        const float* a = &agg[(size_t)n * 16];
#pragma unroll
        for (int k = 0; k < 16; ++k) o[k] = a[k] * inv;
        o[16] = dg > 0 ? 1.f : 0.f;
    }
}

__global__ __launch_bounds__(256) void we17_build(
    const float* __restrict__ epw, const float* __restrict__ epb,
    const float* __restrict__ we_all, float* __restrict__ we17_all) {
    int j = blockIdx.x * 256 + threadIdx.x;
    int kk = blockIdx.y, l = blockIdx.z;
    const float* we = we_all + (size_t)l * D * D;
    float* we17 = we17_all + (size_t)l * 17 * D;
    float acc[17];
#pragma unroll
    for (int i = 0; i < 17; ++i) acc[i] = 0.f;
    for (int k = kk * 128; k < kk * 128 + 128; ++k) {
        float wkj = we[(size_t)k * 512 + j];
#pragma unroll
        for (int i = 0; i < 16; ++i) acc[i] += epw[(size_t)i * 512 + k] * wkj;
        acc[16] += epb[k] * wkj;
    }
#pragma unroll
    for (int i = 0; i < 17; ++i) atomicAdd(&we17[(size_t)i * 512 + j], acc[i]);
}

// ---------------------------------------------------------------------------
// GATv2 per-node
// ---------------------------------------------------------------------------
__global__ __launch_bounds__(256) void gat_node(
    const float* __restrict__ xl, const float* __restrict__ xr,
    const float* __restrict__ ein, const float* __restrict__ we17,
    const int* __restrict__ off, const int* __restrict__ adj,
    const int* __restrict__ ei, const float* __restrict__ att,
    float* __restrict__ out)
{
    __shared__ float we[17][512];
    __shared__ float sc[4][88];
    int tid = threadIdx.x;
    for (int i = tid; i < 17 * 512; i += 256) we[i >> 9][i & 511] = we17[i];
    __syncthreads();
    int wv = tid >> 6, lane = tid & 63;
    int n = blockIdx.x * 4 + wv;
    float xr8[8], att8[8];
#pragma unroll
    for (int i = 0; i < 8; ++i) {
        int d = lane + i * 64;
        xr8[i] = xr[(size_t)n * D + d];
        att8[i] = att[d];
    }
    int o0 = off[n];
    int deg = off[n + 1] - o0;
    if (deg > 80) deg = 80;
    for (int j = 0; j <= deg; ++j) {
        int er, s;
        if (j < deg) { int e = adj[o0 + j]; er = e; s = ei[e]; }
        else         { er = EE + n; s = n; }
        const float* ep = &ein[(size_t)er * 17];
        float e17[17];
#pragma unroll
        for (int k = 0; k < 17; ++k) e17[k] = ep[k];
        float a = 0;
#pragma unroll
        for (int i = 0; i < 8; ++i) {
            int d = lane + i * 64;
            float m = xl[(size_t)s * D + d] + xr8[i];
#pragma unroll
            for (int k = 0; k < 17; ++k) m += e17[k] * we[k][d];
            m = m > 0.f ? m : 0.2f * m;
            a += att8[i] * m;
        }
        a = wsum(a);
        if (lane == 0) sc[wv][j] = a;
    }
    __syncthreads();
    float mx = -1e30f;
    for (int j = 0; j <= deg; ++j) mx = fmaxf(mx, sc[wv][j]);
    float z = 0;
    for (int j = 0; j <= deg; ++j) z += expf(sc[wv][j] - mx);
    float acc[8] = {};
    for (int j = 0; j <= deg; ++j) {
        int s = (j < deg) ? ei[adj[o0 + j]] : n;
        float w = expf(sc[wv][j] - mx);
#pragma unroll
        for (int i = 0; i < 8; ++i) acc[i] += w * xl[(size_t)s * D + lane + i * 64];
    }
    float inv = 1.f / z;
#pragma unroll
    for (int i = 0; i < 8; ++i) out[(size_t)n * D + lane + i * 64] = acc[i] * inv;
}

// ---------------------------------------------------------------------------
// Ring helpers
// ---------------------------------------------------------------------------
__global__ void gather_rows(const float* __restrict__ src, const int* __restrict__ idx,
                            float* __restrict__ dst, int nrows) {
    int i = blockIdx.x * 256 + threadIdx.x;
    int r = i >> 9;
    if (r >= nrows) return;
    dst[i] = src[(size_t)idx[r] * D + (i & 511)];
}

__global__ __launch_bounds__(256) void ring_attn(
    const float* __restrict__ q, const float* __restrict__ k,
    const float* __restrict__ v, float* __restrict__ o)
{
    int rh = blockIdx.x, r = rh >> 1, hh = rh & 1;
    __shared__ float qs[RS * 256], ks[RS * 256], vs[RS * 256];
    __shared__ float scs[36], pr[36];
    int tid = threadIdx.x;
    size_t base = (size_t)r * RS * D + hh * 256;
    for (int i = tid; i < RS * 256; i += 256) {
        int si = i >> 8, d = i & 255;
        size_t g = base + (size_t)si * D + d;
        qs[i] = q[g]; ks[i] = k[g]; vs[i] = v[g];
    }
    __syncthreads();
    if (tid < 36) {
        int i = tid / 6, j = tid % 6;
        float a = 0;
        for (int d = 0; d < 256; ++d) a += qs[i * 256 + d] * ks[j * 256 + d];
        scs[tid] = a * (1.f / 16.f);
    }
    __syncthreads();
    if (tid < 6) {
        float mx = -1e30f;
        for (int j = 0; j < 6; ++j) mx = fmaxf(mx, scs[tid * 6 + j]);
        float p[6], s = 0;
        for (int j = 0; j < 6; ++j) { p[j] = expf(scs[tid * 6 + j] - mx); s += p[j]; }
        for (int j = 0; j < 6; ++j) pr[tid * 6 + j] = p[j] / s;
    }
    __syncthreads();
    for (int i = tid; i < RS * 256; i += 256) {
        int si = i >> 8, d = i & 255;
        float a = 0;
        for (int j = 0; j < 6; ++j) a += pr[si * 6 + j] * vs[j * 256 + d];
        o[base + (size_t)si * D + d] = a;
    }
}

// ---------------------------------------------------------------------------
// mol_attn3: fused per-(b,h), row stride rs for q/k/v (merged QKV layout).
// ---------------------------------------------------------------------------
constexpr int ATT_K_H  = SEQS * 128;
constexpr int ATT_V_ROW = 152;
constexpr int ATT_V_H  = 128 * ATT_V_ROW;
constexpr int ATT_PS_ROW = 144;
constexpr int ATT_PS_H = 8 * ATT_PS_ROW;
constexpr int ATT_SMEM = (ATT_K_H + ATT_V_H + ATT_PS_H) * 2 + 8 * 64 * 4;  // 78848 B

__global__ __launch_bounds__(256) void mol_attn3(
    const float* __restrict__ q, const float* __restrict__ k,
    const float* __restrict__ v, float* __restrict__ o, int rs)
{
    extern __shared__ char smem[];
    _Float16* Ksh = (_Float16*)smem;
    _Float16* Vt  = Ksh + ATT_K_H;
    _Float16* ps  = Vt + ATT_V_H;
    half2_t*  qs  = (half2_t*)(ps + ATT_PS_H);
    const int tid = threadIdx.x, wv = tid >> 6, lane = tid & 63;
    const int b = blockIdx.x >> 2, hh = blockIdx.x & 3;
    const size_t hb = (size_t)b * SEQS * rs + hh * 128;
    const size_t ob = (size_t)b * SEQS * D + hh * 128;

    for (int i = tid; i < SEQS * 32; i += 256) {
        int j = i >> 5, d4 = i & 31;
        float4 kv = *(const float4*)&k[hb + (size_t)j * rs + d4 * 4];
        int off = j * 128 + (((d4 >> 1) ^ (j & 7)) << 3) + ((d4 & 1) << 2);
        *(half2_t*)(Ksh + off)     = half2_t{(_Float16)kv.x, (_Float16)kv.y};
        *(half2_t*)(Ksh + off + 2) = half2_t{(_Float16)kv.z, (_Float16)kv.w};
    }
    for (int i = tid; i < SEQS * 32; i += 256) {
        int j = i >> 5, d4 = i & 31;
        float4 vv = *(const float4*)&v[hb + (size_t)j * rs + d4 * 4];
        Vt[(d4 * 4 + 0) * ATT_V_ROW + j] = (_Float16)vv.x;
        Vt[(d4 * 4 + 1) * ATT_V_ROW + j] = (_Float16)vv.y;
        Vt[(d4 * 4 + 2) * ATT_V_ROW + j] = (_Float16)vv.z;
        Vt[(d4 * 4 + 3) * ATT_V_ROW + j] = (_Float16)vv.w;
    }
    for (int i = tid; i < 128 * 5; i += 256) {
        int d = i / 5, jt = SEQS + i % 5;
        Vt[d * ATT_V_ROW + jt] = (_Float16)0.f;
    }
    __syncthreads();

    const float scale = 0.08838834764831845f;
    for (int t = 0; t < 18; ++t) {
        int p = wv + 4 * t;
        if (p >= 70) continue;
        int q0 = 2 * p, q1 = 2 * p + 1;
        bool h1 = q1 < SEQS;
        {
            float2 f0 = *(const float2*)&q[hb + (size_t)q0 * rs + lane * 2];
            qs[(wv * 2 + 0) * 64 + lane] = half2_t{(_Float16)f0.x, (_Float16)f0.y};
            if (h1) {
                float2 f1 = *(const float2*)&q[hb + (size_t)q1 * rs + lane * 2];
                qs[(wv * 2 + 1) * 64 + lane] = half2_t{(_Float16)f1.x, (_Float16)f1.y};
            }
        }
        float s0[3], s1[3];
#pragma unroll
        for (int jj = 0; jj < 3; ++jj) { s0[jj] = -1e30f; s1[jj] = -1e30f; }
#pragma unroll
        for (int jj = 0; jj < 3; ++jj) {
            int j = lane + jj * 64;
            if (j < SEQS) {
                float a0 = 0, a1 = 0;
                const int jb = j * 128, jx = j & 7;
#pragma unroll
                for (int c = 0; c < 16; ++c) {
                    half8_t kk = *(const half8_t*)(Ksh + jb + ((c ^ jx) << 3));
                    half8_t q0v = *(const half8_t*)(qs + (wv * 2 + 0) * 64 + c * 4);
                    a0 = dot8(kk, q0v, a0);
                    if (h1) {
                        half8_t q1v = *(const half8_t*)(qs + (wv * 2 + 1) * 64 + c * 4);
                        a1 = dot8(kk, q1v, a1);
                    }
                }
                s0[jj] = a0 * scale; s1[jj] = a1 * scale;
            }
        }
        {
            float m0 = wmax(fmaxf(fmaxf(s0[0], s0[1]), s0[2]));
            float z0 = 0; float e0[3];
#pragma unroll
            for (int jj = 0; jj < 3; ++jj) {
                int j = lane + jj * 64;
                e0[jj] = (j < SEQS) ? expf(s0[jj] - m0) : 0.f;
                z0 += e0[jj];
            }
            z0 = wsum(z0); float inv0 = 1.f / z0;
#pragma unroll
            for (int jj = 0; jj < 3; ++jj) {
                int j = lane + jj * 64;
                if (j < ATT_PS_ROW) ps[(wv * 2 + 0) * ATT_PS_ROW + j] = (_Float16)(e0[jj] * inv0);
            }
        }
        if (h1) {
            float m1 = wmax(fmaxf(fmaxf(s1[0], s1[1]), s1[2]));
            float z1 = 0; float e1[3];
#pragma unroll
            for (int jj = 0; jj < 3; ++jj) {
                int j = lane + jj * 64;
                e1[jj] = (j < SEQS) ? expf(s1[jj] - m1) : 0.f;
                z1 += e1[jj];
            }
            z1 = wsum(z1); float inv1 = 1.f / z1;
#pragma unroll
            for (int jj = 0; jj < 3; ++jj) {
                int j = lane + jj * 64;
                if (j < ATT_PS_ROW) ps[(wv * 2 + 1) * ATT_PS_ROW + j] = (_Float16)(e1[jj] * inv1);
            }
        }
        float o00 = 0, o01 = 0, o10 = 0, o11 = 0;
#pragma unroll
        for (int c8 = 0; c8 < 18; ++c8) {
            half8_t va = *(const half8_t*)(Vt + lane * ATT_V_ROW + c8 * 8);
            half8_t vb = *(const half8_t*)(Vt + (lane + 64) * ATT_V_ROW + c8 * 8);
            half8_t p0 = *(const half8_t*)(ps + (wv * 2 + 0) * ATT_PS_ROW + c8 * 8);
            o00 = dot8(va, p0, o00);
            o01 = dot8(vb, p0, o01);
            if (h1) {
                half8_t p1 = *(const half8_t*)(ps + (wv * 2 + 1) * ATT_PS_ROW + c8 * 8);
                o10 = dot8(va, p1, o10);
                o11 = dot8(vb, p1, o11);
            }
        }
        o[ob + (size_t)q0 * D + lane]      = o00;
        o[ob + (size_t)q0 * D + lane + 64] = o01;
        if (h1) {
            o[ob + (size_t)q1 * D + lane]      = o10;
            o[ob + (size_t)q1 * D + lane + 64] = o11;
        }
    }
}

__global__ void ring_pick(const float* __restrict__ t, float* __restrict__ rv) {
    int i = blockIdx.x * 256 + threadIdx.x;
    if (i >= RGS * D) return;
    int r = i >> 9, d = i & 511;
    const float* p = &t[(size_t)r * RS * D + d];
    float best = p[0], ba = fabsf(best);
#pragma unroll
    for (int s = 1; s < RS; ++s) {
        float x = p[(size_t)s * D];
        float ax = fabsf(x);
        if (ax > ba) { ba = ax; best = x; }
    }
    rv[i] = best;
}

__global__ void assemble(const float* __restrict__ h, const float* __restrict__ rv,
                         const float* __restrict__ cls, const float* __restrict__ ringt,
                         const float* __restrict__ endt, float* __restrict__ seq) {
    int i = blockIdx.x * 256 + threadIdx.x;
    if (i >= NSEQ * D) return;
    int row = i >> 9, d = i & 511;
    int b = row / SEQS, p = row % SEQS;
    float val;
    if (p == 0)        val = cls[d];
    else if (p <= 128) val = h[((size_t)b * 128 + (p - 1)) * D + d];
    else if (p == 129) val = ringt[d];
    else if (p <= 137) val = rv[((size_t)b * 8 + (p - 130)) * D + d];
    else               val = endt[d];
    seq[i] = val;
}

// ---------------------------------------------------------------------------
extern "C" void kernel_launch(void* const* d_in, const int* in_sizes, int n_in,
                              void* d_out, int out_size, void* d_ws, size_t ws_size,
                              hipStream_t stream) {
    (void)in_sizes; (void)n_in; (void)out_size; (void)ws_size;

    const float* x          = (const float*)d_in[0];
    const float* edge_attr  = (const float*)d_in[1];
    const int*   ei         = (const int*)  d_in[2];
    const int*   rings_idx  = (const int*)  d_in[3];
    const float* x_proj_w   = (const float*)d_in[8];
    const float* x_proj_b   = (const float*)d_in[9];
    const float* e_proj_w   = (const float*)d_in[10];
    const float* e_proj_b   = (const float*)d_in[11];
    const float* gat_wl     = (const float*)d_in[12];
    const float* gat_bl     = (const float*)d_in[13];
    const float* gat_wr     = (const float*)d_in[14];
    const float* gat_br     = (const float*)d_in[15];
    const float* gat_we     = (const float*)d_in[16];
    const float* gat_att    = (const float*)d_in[17];
    const float* gat_bias   = (const float*)d_in[18];
    const float* gat_ln     = (const float*)d_in[19];
    const float* ring_attn_w= (const float*)d_in[20];
    const float* ring_attn_b= (const float*)d_in[21];
    const float* ring_w1    = (const float*)d_in[22];
    const float* ring_b1    = (const float*)d_in[23];
    const float* ring_w2    = (const float*)d_in[24];
    const float* ring_b2    = (const float*)d_in[25];
    const float* ring_ln    = (const float*)d_in[26];
    const float* mol_attn_w = (const float*)d_in[27];
    const float* mol_attn_b = (const float*)d_in[28];
    const float* mol_w1     = (const float*)d_in[29];
    const float* mol_b1     = (const float*)d_in[30];
    const float* mol_w2     = (const float*)d_in[31];
    const float* mol_b2     = (const float*)d_in[32];
    const float* mol_ln     = (const float*)d_in[33];
    const float* cls_tok    = (const float*)d_in[34];
    const float* ring_tok   = (const float*)d_in[35];
    const float* end_tok    = (const float*)d_in[36];

    constexpr size_t MB = 1024 * 1024;
    char* wsb = (char*)d_ws;
#define WSF(off) ((float*)(wsb + (size_t)(off)))
#define WSI(off) ((int*)(wsb + (size_t)(off)))
#define WSU(off) ((unsigned short*)(wsb + (size_t)(off)))

    // ---- GAT phase ----
    float* H    = WSF(0);
    float* XL   = WSF(16 * MB);
    float* XR   = WSF(32 * MB);
    float* HN   = WSF(48 * MB);
    float* EIN  = WSF(64 * MB);
    float* WE17 = WSF(67 * MB);
    float* AGG  = WSF(68 * MB);
    int*   DEGI = WSI(68 * MB + 512 * 1024);
    int*   OFF  = WSI(68 * MB + 576 * 1024);
    int*   CNT  = WSI(68 * MB + 640 * 1024);
    int*   ADJ  = WSI(68 * MB + 704 * 1024);
    float* RVEC = WSF(70 * MB);

    // ---- ring phase ----
    float* T    = WSF(71 * MB);
    float* RQ   = WSF(77 * MB);
    float* RK   = WSF(83 * MB);
    float* RV   = WSF(89 * MB);
    float* RO   = WSF(95 * MB);
    float* OP   = WSF(101 * MB);          // [2][3072][512] O partials
    float* RY   = WSF(113 * MB);
    float* RFF  = WSF(119 * MB);          // [3072][2048]
    float* W2P  = WSF(143 * MB);          // [4][3072][512] W2 partials
    float* RT2  = WSF(167 * MB);

    // ---- mol phase ----
    float* SEQ  = WSF(71 * MB);
    float* MQKV = WSF(89 * MB);           // [8960][1536] f32 = 52.5MB
    float* MO   = WSF(142 * MB);          // [8960][512]
    unsigned short* ACTh = WSU(161 * MB);
    unsigned short* ACTl = WSU(170 * MB);
    unsigned short* WQKVh = WSU(179 * MB);  // [1536][512]
    unsigned short* WQKVl = WSU(181 * MB);
    unsigned short* WOh  = WSU(183 * MB);
    unsigned short* WOl  = WSU(183 * MB + 512 * 1024);
    unsigned short* W1h  = WSU(184 * MB);
    unsigned short* W1l  = WSU(186 * MB);
    unsigned short* W2h  = WSU(188 * MB);
    unsigned short* W2l  = WSU(190 * MB);
    float* MTMP = WSF(89 * MB);           // over MQKV (dead after attn)
    float* MY   = WSF(107 * MB);
    unsigned short* MFFh = WSU(125 * MB); // [8960][2048] over MQKV tail + MO
    unsigned short* MFFl = WSU(16 * MB);  // over XL/XR/HN (dead)
    float* MT2  = WSF(71 * MB);           // over SEQ (dead)

    dim3 blk(256);

    // ---- phase 0: preprocessing ----
    hipMemsetAsync(DEGI, 0, NN * 4, stream);
    hipMemsetAsync(CNT, 0, NN * 4, stream);
    hipMemsetAsync(AGG, 0, (size_t)NN * 16 * 4, stream);
    hipMemsetAsync(WE17, 0, (size_t)6 * 17 * D * 4, stream);
    deg_int<<<EE / 256, blk, 0, stream>>>(ei, DEGI);
    scan_deg<<<1, blk, 0, stream>>>(DEGI, OFF);
    csr_fill<<<EE / 256, blk, 0, stream>>>(ei, CNT, OFF, ADJ);
    eagg_acc<<<EE * 16 / 256, blk, 0, stream>>>(edge_attr, ei, AGG);
    ein_build<<<ENL / 256, blk, 0, stream>>>(edge_attr, AGG, DEGI, EIN);
    we17_build<<<dim3(2, 4, 6), blk, 0, stream>>>(e_proj_w, e_proj_b, gat_we, WE17);

    // ---- phase 1: x projection (K=64) ----
    {
        GB g{x, x_proj_w, nullptr, nullptr, x_proj_b, nullptr, nullptr,
             H, nullptr, nullptr, NN, D, 64, 1, 1, 64, 0};
        gemm_f32b<<<dim3(D / 64, NN / 128, 1), blk, 0, stream>>>(g);
    }

    // ---- phase 2: 6x GATv2 (f32, batched z=2, no split-K) ----
    for (int l = 0; l < 6; ++l) {
        GB g{H, gat_wl + (size_t)l * D * D, gat_wr + (size_t)l * D * D, nullptr,
             gat_bl + l * D, gat_br + l * D, nullptr,
             XL, XR, nullptr, NN, D, D, 1, 1, D, 0};
        gemm_f32b<<<dim3(D / 64, NN / 128, 2), blk, 0, stream>>>(g);
        gat_node<<<NN / 4, blk, 0, stream>>>(XL, XR, EIN, WE17 + (size_t)l * 17 * D,
                                             OFF, ADJ, ei, gat_att + l * D, HN);
        if (l < 5) {
            ln_rows<<<NN / 4, blk, 0, stream>>>(HN, nullptr, gat_bias + l * D,
                gat_ln + (size_t)l * 2 * D, gat_ln + (size_t)l * 2 * D + D, H, NN, 3, 1);
        } else {
            ln_rows<<<NN / 4, blk, 0, stream>>>(HN, nullptr, gat_bias + l * D,
                nullptr, nullptr, H, NN, 0, 1);
        }
    }

    // ---- phase 3: ring encoder (f32) ----
    const int RROWS = RGS * RS;  // 3072
    gather_rows<<<RROWS * D / 256, blk, 0, stream>>>(H, rings_idx, T, RROWS);
    {   // QKV batched z=3
        GB g{T, ring_attn_w + 0 * D * D, ring_attn_w + 1 * D * D, ring_attn_w + 2 * D * D,
             ring_attn_b + 0 * D, ring_attn_b + 1 * D, ring_attn_b + 2 * D,
             RQ, RK, RV, RROWS, D, D, 1, 1, D, 0};
        gemm_f32b<<<dim3(D / 64, RROWS / 128, 3), blk, 0, stream>>>(g);
    }
    ring_attn<<<RGS * 2, blk, 0, stream>>>(RQ, RK, RV, RO);
    {   // O projection: 2-part partials, bias folded in ln
        GB g{RO, ring_attn_w + 3 * D * D, nullptr, nullptr, nullptr, nullptr, nullptr,
             OP, nullptr, nullptr, RROWS, D, D, 0, 2, 256, (long long)RROWS * D};
        gemm_f32b<<<dim3(D / 64, RROWS / 128, 2), blk, 0, stream>>>(g);
    }
    ln_rows<<<RROWS / 4, blk, 0, stream>>>(OP, T, ring_attn_b + 3 * D,
                                           ring_ln, ring_ln + D, RY, RROWS, 2, 2);
    {   // W1: bias + relu epilogue, single-K
        GB g{RY, ring_w1, nullptr, nullptr, ring_b1, nullptr, nullptr,
             RFF, nullptr, nullptr, RROWS, DFF, D, 3, 1, D, 0};
        gemm_f32b<<<dim3(DFF / 64, RROWS / 128, 1), blk, 0, stream>>>(g);
    }
    {   // W2: 4-part partials
        GB g{RFF, ring_w2, nullptr, nullptr, nullptr, nullptr, nullptr,
             W2P, nullptr, nullptr, RROWS, D, DFF, 0, 4, 512, (long long)RROWS * D};
        gemm_f32b<<<dim3(D / 64, RROWS / 128, 4), blk, 0, stream>>>(g);
    }
    ln_rows<<<RROWS / 4, blk, 0, stream>>>(W2P, RY, ring_b2,
                                           ring_ln + 2 * D, ring_ln + 3 * D, RT2, RROWS, 2, 4);
    ring_pick<<<RGS * D / 256, blk, 0, stream>>>(RT2, RVEC);

    // ---- phase 4: mol encoder (MFMA bf16x3 + fused f16 attention) ----
    assemble<<<(NSEQ * D) / 256, blk, 0, stream>>>(H, RVEC, cls_tok, ring_tok, end_tok, SEQ);
    for (int z = 0; z < 3; ++z)
        wsplitT<<<(D * D + 255) / 256, blk, 0, stream>>>(
            mol_attn_w + (size_t)z * D * D, WQKVh + (size_t)z * D * D, WQKVl + (size_t)z * D * D, D, D);
    wsplitT<<<(D * D + 255) / 256, blk, 0, stream>>>(mol_attn_w + 3 * (size_t)D * D, WOh, WOl, D, D);
    wsplitT<<<(D * DFF + 255) / 256, blk, 0, stream>>>(mol_w1, W1h, W1l, D, DFF);
    wsplitT<<<(DFF * D + 255) / 256, blk, 0, stream>>>(mol_w2, W2h, W2l, DFF, D);

    const int N4_512 = MHAT * D / 4;
    float* MQ = MQKV;
    float* MK = MQKV + 512;
    float* MV = MQKV + 1024;
    asplit4<<<(N4_512 + 255) / 256, blk, 0, stream>>>(SEQ, ACTh, ACTl, N4_512);
    // merged QKV: N = 1536 (bias rows 0..2 of mol_attn_b contiguous)
    gemm_split3<<<dim3(1536 / 128, MHAT / 128), blk, 0, stream>>>(
        ACTh, ACTl, WQKVh, WQKVl, mol_attn_b, MQKV, nullptr, nullptr, 1536, D, 1);

    hipFuncSetAttribute(reinterpret_cast<const void*>(mol_attn3),
                        hipFuncAttributeMaxDynamicSharedMemorySize, ATT_SMEM);
    mol_attn3<<<BMOL * 4, blk, ATT_SMEM, stream>>>(MQ, MK, MV, MO, 1536);

    asplit4<<<(N4_512 + 255) / 256, blk, 0, stream>>>(MO, ACTh, ACTl, N4_512);
    gemm_split3<<<dim3(D / 128, MHAT / 128), blk, 0, stream>>>(
        ACTh, ACTl, WOh, WOl, mol_attn_b + 3 * D, MTMP, nullptr, nullptr, D, D, 1);
    ln_rows<<<(NSEQ + 3) / 4, blk, 0, stream>>>(MTMP, SEQ, nullptr,
                                                mol_ln, mol_ln + D, MY, NSEQ, 2, 1);
    asplit4<<<(N4_512 + 255) / 256, blk, 0, stream>>>(MY, ACTh, ACTl, N4_512);
    gemm_split3<<<dim3(DFF / 128, MHAT / 128), blk, 0, stream>>>(
        ACTh, ACTl, W1h, W1l, mol_b1, nullptr, MFFh, MFFl, DFF, D, 1 | 2 | 4);
    gemm_split3<<<dim3(D / 128, MHAT / 128), blk, 0, stream>>>(
        MFFh, MFFl, W2h, W2l, mol_b2, MT2, nullptr, nullptr, D, DFF, 1);

    float* outf = (float*)d_out;
    ln_rows<<<(NSEQ + 3) / 4, blk, 0, stream>>>(MT2, MY, nullptr,
                                                mol_ln + 2 * D, mol_ln + 3 * D, outf, NSEQ, 2, 1);
    fill_f32<<<(BMOL * 128 + BMOL * 8 + 255) / 256, blk, 0, stream>>>(
        outf + (size_t)NSEQ * D, 1.0f, BMOL * 128 + BMOL * 8);
}

// Round 10
// 2229.970 us; speedup vs baseline: 2.4152x; 1.0138x over previous
//
#include <hip/hip_runtime.h>
#include <math.h>

// ---------------------------------------------------------------------------
// Round 10: XCD-contiguous tile swizzle (T1) in both GEMMs — HW round-robins
// blockIdx%8 across XCDs, so without the swizzle the N-tiles sharing an
// A-panel land on different XCD L2s (8x A over-fetch: split3 FETCH=167MB vs
// ~21MB logical). Swizzle lt -> (lt&7)*(nwg/8) + (lt>>3) gives each XCD a
// contiguous tile chunk. mol_attn3: grid x2 (query halves) -> 2 blocks/CU.
// ---------------------------------------------------------------------------

#define DEV __device__ __forceinline__

constexpr int NN   = 8192;
constexpr int EE   = 32768;
constexpr int ENL  = EE + NN;
constexpr int D    = 512;
constexpr int RGS  = 512;
constexpr int RS   = 6;
constexpr int BMOL = 64;
constexpr int SEQS = 139;
constexpr int NSEQ = BMOL * SEQS;  // 8896
constexpr int MHAT = 8960;         // 70 tiles of 128
constexpr int DFF  = 2048;

typedef short bf8 __attribute__((ext_vector_type(8)));
typedef float f32x4 __attribute__((ext_vector_type(4)));
typedef _Float16 half2_t __attribute__((ext_vector_type(2)));
typedef _Float16 half8_t __attribute__((ext_vector_type(8)));

#ifdef __has_builtin
#if __has_builtin(__builtin_amdgcn_fdot2)
#define HAS_FDOT2 1
#endif
#endif
#ifndef HAS_FDOT2
#define HAS_FDOT2 0
#endif

DEV float wsum(float v) {
    for (int o = 32; o > 0; o >>= 1) v += __shfl_xor(v, o, 64);
    return v;
}
DEV float wmax(float v) {
    for (int o = 32; o > 0; o >>= 1) v = fmaxf(v, __shfl_xor(v, o, 64));
    return v;
}
DEV unsigned short f2bf(float x) {
    unsigned u = __float_as_uint(x);
    u += 0x7FFFu + ((u >> 16) & 1u);
    return (unsigned short)(u >> 16);
}
DEV float bf2f(unsigned short h) { return __uint_as_float((unsigned)h << 16); }

DEV float dot8(half8_t a, half8_t b, float acc) {
#if HAS_FDOT2
    acc = __builtin_amdgcn_fdot2(__builtin_shufflevector(a, a, 0, 1),
                                 __builtin_shufflevector(b, b, 0, 1), acc, false);
    acc = __builtin_amdgcn_fdot2(__builtin_shufflevector(a, a, 2, 3),
                                 __builtin_shufflevector(b, b, 2, 3), acc, false);
    acc = __builtin_amdgcn_fdot2(__builtin_shufflevector(a, a, 4, 5),
                                 __builtin_shufflevector(b, b, 4, 5), acc, false);
    acc = __builtin_amdgcn_fdot2(__builtin_shufflevector(a, a, 6, 7),
                                 __builtin_shufflevector(b, b, 6, 7), acc, false);
#else
#pragma unroll
    for (int i = 0; i < 8; ++i) acc += (float)a[i] * (float)b[i];
#endif
    return acc;
}

// XCD-contiguous swizzle: HW assigns linear block id % 8 -> XCD. Remap so
// XCD j gets tiles [j*nwg/8, (j+1)*nwg/8) in row-major (n-fastest) order.
// Bijective when nwg % 8 == 0 (all our launches); else identity.
DEV int xcd_swz(int lt, int nwg) {
    if (nwg & 7) return lt;
    return (lt & 7) * (nwg >> 3) + (lt >> 3);
}

// ---------------------------------------------------------------------------
// Batched / split-K f32 GEMM. 128Mx64N tile, 256 thr, 8x4/thread.
// grid: (N/64, M/128, nb*kparts). flags: 1 bias (kp==0), 2 relu (kparts==1).
// split-K writes partials at C + kp*cstride (folded downstream in ln_rows).
// ---------------------------------------------------------------------------
struct GB {
    const float* A;
    const float* B0; const float* B1; const float* B2;
    const float* bias0; const float* bias1; const float* bias2;
    float* C0; float* C1; float* C2;
    int M, N, K, flags, kparts, ksz;
    long long cstride;
};

__global__ __launch_bounds__(256) void gemm_f32b(GB g) {
    __shared__ float As[16][132];
    __shared__ float Bs[16][64];
    const int z = blockIdx.z;
    const int bb = z / g.kparts, kp = z - bb * g.kparts;
    const float* B = bb == 0 ? g.B0 : (bb == 1 ? g.B1 : g.B2);
    const float* bias = bb == 0 ? g.bias0 : (bb == 1 ? g.bias1 : g.bias2);
    float* C = (bb == 0 ? g.C0 : (bb == 1 ? g.C1 : g.C2)) + (size_t)kp * g.cstride;
    const int M = g.M, N = g.N;

    const int nx = gridDim.x;
    const int lt = xcd_swz(blockIdx.x + nx * blockIdx.y, nx * gridDim.y);
    const int mt = lt / nx, ntile = lt - mt * nx;
    const int m0 = mt * 128, n0 = ntile * 64;

    const int tid = threadIdx.x;
    const int tx = tid & 15, ty = tid >> 4;

    const int a_row = tid >> 2;          // 0..63 (+64)
    const int a_kc  = (tid & 3) * 4;
    const int b_row = tid >> 4;          // 0..15
    const int b_cg  = (tid & 15) * 4;

    float acc[8][4] = {};
    const int kbeg = kp * g.ksz, kend = kbeg + g.ksz;
    for (int k0 = kbeg; k0 < kend; k0 += 16) {
#pragma unroll
        for (int i = 0; i < 2; ++i) {
            int r = a_row + i * 64;
            int gr = m0 + r; if (gr >= M) gr = M - 1;
            float4 av = *(const float4*)&g.A[(size_t)gr * g.K + k0 + a_kc];
            As[a_kc + 0][r] = av.x;
            As[a_kc + 1][r] = av.y;
            As[a_kc + 2][r] = av.z;
            As[a_kc + 3][r] = av.w;
        }
        *(float4*)&Bs[b_row][b_cg] =
            *(const float4*)&B[(size_t)(k0 + b_row) * N + n0 + b_cg];
        __syncthreads();
#pragma unroll
        for (int k = 0; k < 16; ++k) {
            float a0[8], b0[4];
            *(float4*)&a0[0] = *(const float4*)&As[k][ty * 8];
            *(float4*)&a0[4] = *(const float4*)&As[k][ty * 8 + 4];
            *(float4*)&b0[0] = *(const float4*)&Bs[k][tx * 4];
#pragma unroll
            for (int i = 0; i < 8; ++i)
#pragma unroll
                for (int j = 0; j < 4; ++j) acc[i][j] += a0[i] * b0[j];
        }
        __syncthreads();
    }
#pragma unroll
    for (int i = 0; i < 8; ++i) {
        int gr = m0 + ty * 8 + i;
        if (gr >= M) break;
        float o0[4];
#pragma unroll
        for (int j = 0; j < 4; ++j) o0[j] = acc[i][j];
        if ((g.flags & 1) && kp == 0) {
            const float* bp = bias + n0 + tx * 4;
#pragma unroll
            for (int j = 0; j < 4; ++j) o0[j] += bp[j];
        }
        if ((g.flags & 2) && g.kparts == 1) {
#pragma unroll
            for (int j = 0; j < 4; ++j) o0[j] = fmaxf(o0[j], 0.f);
        }
        *(float4*)&C[(size_t)gr * N + n0 + tx * 4] =
            make_float4(o0[0], o0[1], o0[2], o0[3]);
    }
}

// ---------------------------------------------------------------------------
// MFMA bf16x3-split GEMM (mol phase). XCD-swizzled tile assignment.
// ---------------------------------------------------------------------------
__global__ __launch_bounds__(256) void gemm_split3(
    const unsigned short* __restrict__ Ah, const unsigned short* __restrict__ Al,
    const unsigned short* __restrict__ Bh, const unsigned short* __restrict__ Bl,
    const float* __restrict__ bias, float* __restrict__ C,
    unsigned short* __restrict__ Ch, unsigned short* __restrict__ Cl,
    int N, int K, int flags)
{
    __shared__ unsigned short sA[2][128][40];
    __shared__ unsigned short sB[2][128][40];
    const int nx = gridDim.x;
    const int lt = xcd_swz(blockIdx.x + nx * blockIdx.y, nx * gridDim.y);
    const int mt = lt / nx, ntile = lt - mt * nx;
    const int m0 = mt * 128, n0 = ntile * 128;

    const int tid = threadIdx.x;
    const int wv = tid >> 6, lane = tid & 63;
    const int srow = tid >> 2, sc8 = (tid & 3) * 8;
    const int mw = (wv & 1) * 64, nw = (wv >> 1) * 64;
    const int fr = lane & 15, fq = lane >> 4;
    const int ko = fq * 8;

    f32x4 acc[4][4];
    f32x4 zero = {0.f, 0.f, 0.f, 0.f};
#pragma unroll
    for (int i = 0; i < 4; ++i)
#pragma unroll
        for (int j = 0; j < 4; ++j) acc[i][j] = zero;

    for (int k0 = 0; k0 < K; k0 += 32) {
#pragma unroll
        for (int h = 0; h < 2; ++h) {
            int r = srow + h * 64;
            *(bf8*)&sA[0][r][sc8] = *(const bf8*)&Ah[(size_t)(m0 + r) * K + k0 + sc8];
            *(bf8*)&sA[1][r][sc8] = *(const bf8*)&Al[(size_t)(m0 + r) * K + k0 + sc8];
            *(bf8*)&sB[0][r][sc8] = *(const bf8*)&Bh[(size_t)(n0 + r) * K + k0 + sc8];
            *(bf8*)&sB[1][r][sc8] = *(const bf8*)&Bl[(size_t)(n0 + r) * K + k0 + sc8];
        }
        __syncthreads();
        bf8 ah[4], al[4], bh[4], bl[4];
#pragma unroll
        for (int t = 0; t < 4; ++t) {
            ah[t] = *(const bf8*)&sA[0][mw + t * 16 + fr][ko];
            al[t] = *(const bf8*)&sA[1][mw + t * 16 + fr][ko];
            bh[t] = *(const bf8*)&sB[0][nw + t * 16 + fr][ko];
            bl[t] = *(const bf8*)&sB[1][nw + t * 16 + fr][ko];
        }
#pragma unroll
        for (int i = 0; i < 4; ++i)
#pragma unroll
            for (int j = 0; j < 4; ++j) {
                acc[i][j] = __builtin_amdgcn_mfma_f32_16x16x32_bf16(ah[i], bh[j], acc[i][j], 0, 0, 0);
                acc[i][j] = __builtin_amdgcn_mfma_f32_16x16x32_bf16(ah[i], bl[j], acc[i][j], 0, 0, 0);
                acc[i][j] = __builtin_amdgcn_mfma_f32_16x16x32_bf16(al[i], bh[j], acc[i][j], 0, 0, 0);
            }
        __syncthreads();
    }
#pragma unroll
    for (int i = 0; i < 4; ++i)
#pragma unroll
        for (int j = 0; j < 4; ++j) {
            int col = n0 + nw + j * 16 + fr;
#pragma unroll
            for (int r = 0; r < 4; ++r) {
                int row = m0 + mw + i * 16 + fq * 4 + r;
                float o = acc[i][j][r];
                if (flags & 1) o += bias[col];
                if (flags & 2) o = fmaxf(o, 0.f);
                size_t idx = (size_t)row * N + col;
                if (flags & 4) {
                    unsigned short hb_ = f2bf(o);
                    Ch[idx] = hb_;
                    Cl[idx] = f2bf(o - bf2f(hb_));
                } else {
                    C[idx] = o;
                }
            }
        }
}

__global__ void asplit4(const float* __restrict__ src, unsigned short* __restrict__ hh,
                        unsigned short* __restrict__ ll, int n4) {
    int i = blockIdx.x * 256 + threadIdx.x;
    if (i >= n4) return;
    float4 v = ((const float4*)src)[i];
    ushort4 h, l;
    h.x = f2bf(v.x); l.x = f2bf(v.x - bf2f(h.x));
    h.y = f2bf(v.y); l.y = f2bf(v.y - bf2f(h.y));
    h.z = f2bf(v.z); l.z = f2bf(v.z - bf2f(h.z));
    h.w = f2bf(v.w); l.w = f2bf(v.w - bf2f(h.w));
    ((ushort4*)hh)[i] = h;
    ((ushort4*)ll)[i] = l;
}

__global__ void wsplitT(const float* __restrict__ w, unsigned short* __restrict__ bh,
                        unsigned short* __restrict__ bl, int K, int N) {
    int i = blockIdx.x * 256 + threadIdx.x;
    if (i >= K * N) return;
    int k = i / N, n = i - k * N;
    float x = w[i];
    unsigned short h = f2bf(x);
    unsigned short l = f2bf(x - bf2f(h));
    bh[(size_t)n * K + k] = h;
    bl[(size_t)n * K + k] = l;
}

// ---------------------------------------------------------------------------
// Row LayerNorm (D=512), wave per row. flags: 1 relu, 2 LN. parts: sum
// split-K partials x[p][rows][D] before (res, bias, LN).
// ---------------------------------------------------------------------------
__global__ __launch_bounds__(256) void ln_rows(
    const float* __restrict__ x, const float* __restrict__ res,
    const float* __restrict__ bias, const float* __restrict__ g,
    const float* __restrict__ be, float* __restrict__ out, int rows, int flags,
    int parts)
{
    int r = blockIdx.x * 4 + (threadIdx.x >> 6);
    if (r >= rows) return;
    int lane = threadIdx.x & 63;
    size_t base = (size_t)r * D;
    size_t pstride = (size_t)rows * D;
    float v[8];
#pragma unroll
    for (int i = 0; i < 8; ++i) {
        int d = lane + i * 64;
        float t = x[base + d];
        for (int p = 1; p < parts; ++p) t += x[p * pstride + base + d];
        if (res)  t += res[base + d];
        if (bias) t += bias[d];
        v[i] = t;
    }
    if (flags & 2) {
        float s = 0;
#pragma unroll
        for (int i = 0; i < 8; ++i) s += v[i];
        float mu = wsum(s) * (1.f / 512.f);
        float q = 0;
#pragma unroll
        for (int i = 0; i < 8; ++i) { float d0 = v[i] - mu; q += d0 * d0; }
        float inv = rsqrtf(wsum(q) * (1.f / 512.f) + 1e-5f);
#pragma unroll
        for (int i = 0; i < 8; ++i) {
            int d = lane + i * 64;
            float o = (v[i] - mu) * inv * g[d] + be[d];
            if (flags & 1) o = fmaxf(o, 0.f);
            out[base + d] = o;
        }
    } else {
#pragma unroll
        for (int i = 0; i < 8; ++i) {
            int d = lane + i * 64;
            float o = v[i];
            if (flags & 1) o = fmaxf(o, 0.f);
            out[base + d] = o;
        }
    }
}

__global__ void fill_f32(float* p, float v, int n) {
    int i = blockIdx.x * 256 + threadIdx.x;
    if (i < n) p[i] = v;
}

// ---------------------------------------------------------------------------
// Graph preprocessing
// ---------------------------------------------------------------------------
__global__ void deg_int(const int* __restrict__ ei, int* __restrict__ degi) {
    int e = blockIdx.x * 256 + threadIdx.x;
    if (e >= EE) return;
    atomicAdd(&degi[ei[EE + e]], 1);
}

__global__ __launch_bounds__(256) void scan_deg(const int* __restrict__ degi,
                                                int* __restrict__ off) {
    __shared__ int ps[256];
    int tid = threadIdx.x;
    int base = tid * 32;
    int loc[32];
    int s = 0;
#pragma unroll
    for (int i = 0; i < 32; ++i) { loc[i] = s; s += degi[base + i]; }
    ps[tid] = s;
    __syncthreads();
    for (int o = 1; o < 256; o <<= 1) {
        int v = (tid >= o) ? ps[tid - o] : 0;
        __syncthreads();
        ps[tid] += v;
        __syncthreads();
    }
    int pre = (tid == 0) ? 0 : ps[tid - 1];
#pragma unroll
    for (int i = 0; i < 32; ++i) off[base + i] = pre + loc[i];
    if (tid == 255) off[8192] = ps[255];
}

__global__ void csr_fill(const int* __restrict__ ei, int* __restrict__ cnt,
                         const int* __restrict__ off, int* __restrict__ adj) {
    int e = blockIdx.x * 256 + threadIdx.x;
    if (e >= EE) return;
    int dn = ei[EE + e];
    int p = atomicAdd(&cnt[dn], 1);
    adj[off[dn] + p] = e;
}

__global__ void eagg_acc(const float* __restrict__ eattr, const int* __restrict__ ei,
                         float* __restrict__ agg) {
    int id = blockIdx.x * 256 + threadIdx.x;
    if (id >= EE * 16) return;
    int e = id >> 4, c = id & 15;
    atomicAdd(&agg[(size_t)ei[EE + e] * 16 + c], eattr[id]);
}

__global__ void ein_build(const float* __restrict__ eattr, const float* __restrict__ agg,
                          const int* __restrict__ degi, float* __restrict__ ein) {
    int r = blockIdx.x * 256 + threadIdx.x;
    if (r >= ENL) return;
    float* o = &ein[(size_t)r * 17];
    if (r < EE) {
        const float* a = &eattr[(size_t)r * 16];
#pragma unroll
        for (int k = 0; k < 16; ++k) o[k] = a[k];
        o[16] = 1.f;
    } else {
        int n = r - EE;
        int dg = degi[n];
        float inv = 1.f / (float)(dg > 1 ? dg : 1);
        const float* a = &agg[(size_t)n * 16];
#pragma unroll
        for (int k = 0; k < 16; ++k) o[k] = a[k] * inv;
        o[16] = dg > 0 ? 1.f : 0.f;
    }
}

__global__ __launch_bounds__(256) void we17_build(
    const float* __restrict__ epw, const float* __restrict__ epb,
    const float* __restrict__ we_all, float* __restrict__ we17_all) {
    int j = blockIdx.x * 256 + threadIdx.x;
    int kk = blockIdx.y, l = blockIdx.z;
    const float* we = we_all + (size_t)l * D * D;
    float* we17 = we17_all + (size_t)l * 17 * D;
    float acc[17];
#pragma unroll
    for (int i = 0; i < 17; ++i) acc[i] = 0.f;
    for (int k = kk * 128; k < kk * 128 + 128; ++k) {
        float wkj = we[(size_t)k * 512 + j];
#pragma unroll
        for (int i = 0; i < 16; ++i) acc[i] += epw[(size_t)i * 512 + k] * wkj;
        acc[16] += epb[k] * wkj;
    }
#pragma unroll
    for (int i = 0; i < 17; ++i) atomicAdd(&we17[(size_t)i * 512 + j], acc[i]);
}

// ---------------------------------------------------------------------------
// GATv2 per-node
// ---------------------------------------------------------------------------
__global__ __launch_bounds__(256) void gat_node(
    const float* __restrict__ xl, const float* __restrict__ xr,
    const float* __restrict__ ein, const float* __restrict__ we17,
    const int* __restrict__ off, const int* __restrict__ adj,
    const int* __restrict__ ei, const float* __restrict__ att,
    float* __restrict__ out)
{
    __shared__ float we[17][512];
    __shared__ float sc[4][88];
    int tid = threadIdx.x;
    for (int i = tid; i < 17 * 512; i += 256) we[i >> 9][i & 511] = we17[i];
    __syncthreads();
    int wv = tid >> 6, lane = tid & 63;
    int n = blockIdx.x * 4 + wv;
    float xr8[8], att8[8];
#pragma unroll
    for (int i = 0; i < 8; ++i) {
        int d = lane + i * 64;
        xr8[i] = xr[(size_t)n * D + d];
        att8[i] = att[d];
    }
    int o0 = off[n];
    int deg = off[n + 1] - o0;
    if (deg > 80) deg = 80;
    for (int j = 0; j <= deg; ++j) {
        int er, s;
        if (j < deg) { int e = adj[o0 + j]; er = e; s = ei[e]; }
        else         { er = EE + n; s = n; }
        const float* ep = &ein[(size_t)er * 17];
        float e17[17];
#pragma unroll
        for (int k = 0; k < 17; ++k) e17[k] = ep[k];
        float a = 0;
#pragma unroll
        for (int i = 0; i < 8; ++i) {
            int d = lane + i * 64;
            float m = xl[(size_t)s * D + d] + xr8[i];
#pragma unroll
            for (int k = 0; k < 17; ++k) m += e17[k] * we[k][d];
            m = m > 0.f ? m : 0.2f * m;
            a += att8[i] * m;
        }
        a = wsum(a);
        if (lane == 0) sc[wv][j] = a;
    }
    __syncthreads();
    float mx = -1e30f;
    for (int j = 0; j <= deg; ++j) mx = fmaxf(mx, sc[wv][j]);
    float z = 0;
    for (int j = 0; j <= deg; ++j) z += expf(sc[wv][j] - mx);
    float acc[8] = {};
    for (int j = 0; j <= deg; ++j) {
        int s = (j < deg) ? ei[adj[o0 + j]] : n;
        float w = expf(sc[wv][j] - mx);
#pragma unroll
        for (int i = 0; i < 8; ++i) acc[i] += w * xl[(size_t)s * D + lane + i * 64];
    }
    float inv = 1.f / z;
#pragma unroll
    for (int i = 0; i < 8; ++i) out[(size_t)n * D + lane + i * 64] = acc[i] * inv;
}

// ---------------------------------------------------------------------------
// Ring helpers
// ---------------------------------------------------------------------------
__global__ void gather_rows(const float* __restrict__ src, const int* __restrict__ idx,
                            float* __restrict__ dst, int nrows) {
    int i = blockIdx.x * 256 + threadIdx.x;
    int r = i >> 9;
    if (r >= nrows) return;
    dst[i] = src[(size_t)idx[r] * D + (i & 511)];
}

__global__ __launch_bounds__(256) void ring_attn(
    const float* __restrict__ q, const float* __restrict__ k,
    const float* __restrict__ v, float* __restrict__ o)
{
    int rh = blockIdx.x, r = rh >> 1, hh = rh & 1;
    __shared__ float qs[RS * 256], ks[RS * 256], vs[RS * 256];
    __shared__ float scs[36], pr[36];
    int tid = threadIdx.x;
    size_t base = (size_t)r * RS * D + hh * 256;
    for (int i = tid; i < RS * 256; i += 256) {
        int si = i >> 8, d = i & 255;
        size_t g = base + (size_t)si * D + d;
        qs[i] = q[g]; ks[i] = k[g]; vs[i] = v[g];
    }
    __syncthreads();
    if (tid < 36) {
        int i = tid / 6, j = tid % 6;
        float a = 0;
        for (int d = 0; d < 256; ++d) a += qs[i * 256 + d] * ks[j * 256 + d];
        scs[tid] = a * (1.f / 16.f);
    }
    __syncthreads();
    if (tid < 6) {
        float mx = -1e30f;
        for (int j = 0; j < 6; ++j) mx = fmaxf(mx, scs[tid * 6 + j]);
        float p[6], s = 0;
        for (int j = 0; j < 6; ++j) { p[j] = expf(scs[tid * 6 + j] - mx); s += p[j]; }
        for (int j = 0; j < 6; ++j) pr[tid * 6 + j] = p[j] / s;
    }
    __syncthreads();
    for (int i = tid; i < RS * 256; i += 256) {
        int si = i >> 8, d = i & 255;
        float a = 0;
        for (int j = 0; j < 6; ++j) a += pr[si * 6 + j] * vs[j * 256 + d];
        o[base + (size_t)si * D + d] = a;
    }
}

// ---------------------------------------------------------------------------
// mol_attn3: fused per-(b,h), row stride rs; grid.y splits the 70 query
// pairs into halves (35 each) -> 512 blocks -> 2 blocks/CU.
// ---------------------------------------------------------------------------
constexpr int ATT_K_H  = SEQS * 128;
constexpr int ATT_V_ROW = 152;
constexpr int ATT_V_H  = 128 * ATT_V_ROW;
constexpr int ATT_PS_ROW = 144;
constexpr int ATT_PS_H = 8 * ATT_PS_ROW;
constexpr int ATT_SMEM = (ATT_K_H + ATT_V_H + ATT_PS_H) * 2 + 8 * 64 * 4;  // 78848 B

__global__ __launch_bounds__(256) void mol_attn3(
    const float* __restrict__ q, const float* __restrict__ k,
    const float* __restrict__ v, float* __restrict__ o, int rs)
{
    extern __shared__ char smem[];
    _Float16* Ksh = (_Float16*)smem;
    _Float16* Vt  = Ksh + ATT_K_H;
    _Float16* ps  = Vt + ATT_V_H;
    half2_t*  qs  = (half2_t*)(ps + ATT_PS_H);
    const int tid = threadIdx.x, wv = tid >> 6, lane = tid & 63;
    const int b = blockIdx.x >> 2, hh = blockIdx.x & 3;
    const int pbeg = blockIdx.y * 35;
    const int pend = min(pbeg + 35, 70);
    const size_t hb = (size_t)b * SEQS * rs + hh * 128;
    const size_t ob = (size_t)b * SEQS * D + hh * 128;

    for (int i = tid; i < SEQS * 32; i += 256) {
        int j = i >> 5, d4 = i & 31;
        float4 kv = *(const float4*)&k[hb + (size_t)j * rs + d4 * 4];
        int off = j * 128 + (((d4 >> 1) ^ (j & 7)) << 3) + ((d4 & 1) << 2);
        *(half2_t*)(Ksh + off)     = half2_t{(_Float16)kv.x, (_Float16)kv.y};
        *(half2_t*)(Ksh + off + 2) = half2_t{(_Float16)kv.z, (_Float16)kv.w};
    }
    for (int i = tid; i < SEQS * 32; i += 256) {
        int j = i >> 5, d4 = i & 31;
        float4 vv = *(const float4*)&v[hb + (size_t)j * rs + d4 * 4];
        Vt[(d4 * 4 + 0) * ATT_V_ROW + j] = (_Float16)vv.x;
        Vt[(d4 * 4 + 1) * ATT_V_ROW + j] = (_Float16)vv.y;
        Vt[(d4 * 4 + 2) * ATT_V_ROW + j] = (_Float16)vv.z;
        Vt[(d4 * 4 + 3) * ATT_V_ROW + j] = (_Float16)vv.w;
    }
    for (int i = tid; i < 128 * 5; i += 256) {
        int d = i / 5, jt = SEQS + i % 5;
        Vt[d * ATT_V_ROW + jt] = (_Float16)0.f;
    }
    __syncthreads();

    const float scale = 0.08838834764831845f;
    for (int t = 0; t < 9; ++t) {
        int p = pbeg + wv + 4 * t;
        if (p >= pend) continue;
        int q0 = 2 * p, q1 = 2 * p + 1;
        bool h1 = q1 < SEQS;
        {
            float2 f0 = *(const float2*)&q[hb + (size_t)q0 * rs + lane * 2];
            qs[(wv * 2 + 0) * 64 + lane] = half2_t{(_Float16)f0.x, (_Float16)f0.y};
            if (h1) {
                float2 f1 = *(const float2*)&q[hb + (size_t)q1 * rs + lane * 2];
                qs[(wv * 2 + 1) * 64 + lane] = half2_t{(_Float16)f1.x, (_Float16)f1.y};
            }
        }
        float s0[3], s1[3];
#pragma unroll
        for (int jj = 0; jj < 3; ++jj) { s0[jj] = -1e30f; s1[jj] = -1e30f; }
#pragma unroll
        for (int jj = 0; jj < 3; ++jj) {
            int j = lane + jj * 64;
            if (j < SEQS) {
                float a0 = 0, a1 = 0;
                const int jb = j * 128, jx = j & 7;
#pragma unroll
                for (int c = 0; c < 16; ++c) {
                    half8_t kk = *(const half8_t*)(Ksh + jb + ((c ^ jx) << 3));
                    half8_t q0v = *(const half8_t*)(qs + (wv * 2 + 0) * 64 + c * 4);
                    a0 = dot8(kk, q0v, a0);
                    if (h1) {
                        half8_t q1v = *(const half8_t*)(qs + (wv * 2 + 1) * 64 + c * 4);
                        a1 = dot8(kk, q1v, a1);
                    }
                }
                s0[jj] = a0 * scale; s1[jj] = a1 * scale;
            }
        }
        {
            float m0 = wmax(fmaxf(fmaxf(s0[0], s0[1]), s0[2]));
            float z0 = 0; float e0[3];
#pragma unroll
            for (int jj = 0; jj < 3; ++jj) {
                int j = lane + jj * 64;
                e0[jj] = (j < SEQS) ? expf(s0[jj] - m0) : 0.f;
                z0 += e0[jj];
            }
            z0 = wsum(z0); float inv0 = 1.f / z0;
#pragma unroll
            for (int jj = 0; jj < 3; ++jj) {
                int j = lane + jj * 64;
                if (j < ATT_PS_ROW) ps[(wv * 2 + 0) * ATT_PS_ROW + j] = (_Float16)(e0[jj] * inv0);
            }
        }
        if (h1) {
            float m1 = wmax(fmaxf(fmaxf(s1[0], s1[1]), s1[2]));
            float z1 = 0; float e1[3];
#pragma unroll
            for (int jj = 0; jj < 3; ++jj) {
                int j = lane + jj * 64;
                e1[jj] = (j < SEQS) ? expf(s1[jj] - m1) : 0.f;
                z1 += e1[jj];
            }
            z1 = wsum(z1); float inv1 = 1.f / z1;
#pragma unroll
            for (int jj = 0; jj < 3; ++jj) {
                int j = lane + jj * 64;
                if (j < ATT_PS_ROW) ps[(wv * 2 + 1) * ATT_PS_ROW + j] = (_Float16)(e1[jj] * inv1);
            }
        }
        float o00 = 0, o01 = 0, o10 = 0, o11 = 0;
#pragma unroll
        for (int c8 = 0; c8 < 18; ++c8) {
            half8_t va = *(const half8_t*)(Vt + lane * ATT_V_ROW + c8 * 8);
            half8_t vb = *(const half8_t*)(Vt + (lane + 64) * ATT_V_ROW + c8 * 8);
            half8_t p0 = *(const half8_t*)(ps + (wv * 2 + 0) * ATT_PS_ROW + c8 * 8);
            o00 = dot8(va, p0, o00);
            o01 = dot8(vb, p0, o01);
            if (h1) {
                half8_t p1 = *(const half8_t*)(ps + (wv * 2 + 1) * ATT_PS_ROW + c8 * 8);
                o10 = dot8(va, p1, o10);
                o11 = dot8(vb, p1, o11);
            }
        }
        o[ob + (size_t)q0 * D + lane]      = o00;
        o[ob + (size_t)q0 * D + lane + 64] = o01;
        if (h1) {
            o[ob + (size_t)q1 * D + lane]      = o10;
            o[ob + (size_t)q1 * D + lane + 64] = o11;
        }
    }
}

__global__ void ring_pick(const float* __restrict__ t, float* __restrict__ rv) {
    int i = blockIdx.x * 256 + threadIdx.x;
    if (i >= RGS * D) return;
    int r = i >> 9, d = i & 511;
    const float* p = &t[(size_t)r * RS * D + d];
    float best = p[0], ba = fabsf(best);
#pragma unroll
    for (int s = 1; s < RS; ++s) {
        float x = p[(size_t)s * D];
        float ax = fabsf(x);
        if (ax > ba) { ba = ax; best = x; }
    }
    rv[i] = best;
}

__global__ void assemble(const float* __restrict__ h, const float* __restrict__ rv,
                         const float* __restrict__ cls, const float* __restrict__ ringt,
                         const float* __restrict__ endt, float* __restrict__ seq) {
    int i = blockIdx.x * 256 + threadIdx.x;
    if (i >= NSEQ * D) return;
    int row = i >> 9, d = i & 511;
    int b = row / SEQS, p = row % SEQS;
    float val;
    if (p == 0)        val = cls[d];
    else if (p <= 128) val = h[((size_t)b * 128 + (p - 1)) * D + d];
    else if (p == 129) val = ringt[d];
    else if (p <= 137) val = rv[((size_t)b * 8 + (p - 130)) * D + d];
    else               val = endt[d];
    seq[i] = val;
}

// ---------------------------------------------------------------------------
extern "C" void kernel_launch(void* const* d_in, const int* in_sizes, int n_in,
                              void* d_out, int out_size, void* d_ws, size_t ws_size,
                              hipStream_t stream) {
    (void)in_sizes; (void)n_in; (void)out_size; (void)ws_size;

    const float* x          = (const float*)d_in[0];
    const float* edge_attr  = (const float*)d_in[1];
    const int*   ei         = (const int*)  d_in[2];
    const int*   rings_idx  = (const int*)  d_in[3];
    const float* x_proj_w   = (const float*)d_in[8];
    const float* x_proj_b   = (const float*)d_in[9];
    const float* e_proj_w   = (const float*)d_in[10];
    const float* e_proj_b   = (const float*)d_in[11];
    const float* gat_wl     = (const float*)d_in[12];
    const float* gat_bl     = (const float*)d_in[13];
    const float* gat_wr     = (const float*)d_in[14];
    const float* gat_br     = (const float*)d_in[15];
    const float* gat_we     = (const float*)d_in[16];
    const float* gat_att    = (const float*)d_in[17];
    const float* gat_bias   = (const float*)d_in[18];
    const float* gat_ln     = (const float*)d_in[19];
    const float* ring_attn_w= (const float*)d_in[20];
    const float* ring_attn_b= (const float*)d_in[21];
    const float* ring_w1    = (const float*)d_in[22];
    const float* ring_b1    = (const float*)d_in[23];
    const float* ring_w2    = (const float*)d_in[24];
    const float* ring_b2    = (const float*)d_in[25];
    const float* ring_ln    = (const float*)d_in[26];
    const float* mol_attn_w = (const float*)d_in[27];
    const float* mol_attn_b = (const float*)d_in[28];
    const float* mol_w1     = (const float*)d_in[29];
    const float* mol_b1     = (const float*)d_in[30];
    const float* mol_w2     = (const float*)d_in[31];
    const float* mol_b2     = (const float*)d_in[32];
    const float* mol_ln     = (const float*)d_in[33];
    const float* cls_tok    = (const float*)d_in[34];
    const float* ring_tok   = (const float*)d_in[35];
    const float* end_tok    = (const float*)d_in[36];

    constexpr size_t MB = 1024 * 1024;
    char* wsb = (char*)d_ws;
#define WSF(off) ((float*)(wsb + (size_t)(off)))
#define WSI(off) ((int*)(wsb + (size_t)(off)))
#define WSU(off) ((unsigned short*)(wsb + (size_t)(off)))

    // ---- GAT phase ----
    float* H    = WSF(0);
    float* XL   = WSF(16 * MB);
    float* XR   = WSF(32 * MB);
    float* HN   = WSF(48 * MB);
    float* EIN  = WSF(64 * MB);
    float* WE17 = WSF(67 * MB);
    float* AGG  = WSF(68 * MB);
    int*   DEGI = WSI(68 * MB + 512 * 1024);
    int*   OFF  = WSI(68 * MB + 576 * 1024);
    int*   CNT  = WSI(68 * MB + 640 * 1024);
    int*   ADJ  = WSI(68 * MB + 704 * 1024);
    float* RVEC = WSF(70 * MB);

    // ---- ring phase ----
    float* T    = WSF(71 * MB);
    float* RQ   = WSF(77 * MB);
    float* RK   = WSF(83 * MB);
    float* RV   = WSF(89 * MB);
    float* RO   = WSF(95 * MB);
    float* OP   = WSF(101 * MB);          // [2][3072][512] O partials
    float* RY   = WSF(113 * MB);
    float* RFF  = WSF(119 * MB);          // [3072][2048]
    float* W2P  = WSF(143 * MB);          // [4][3072][512] W2 partials
    float* RT2  = WSF(167 * MB);

    // ---- mol phase ----
    float* SEQ  = WSF(71 * MB);
    float* MQKV = WSF(89 * MB);           // [8960][1536] f32 = 52.5MB
    float* MO   = WSF(142 * MB);          // [8960][512]
    unsigned short* ACTh = WSU(161 * MB);
    unsigned short* ACTl = WSU(170 * MB);
    unsigned short* WQKVh = WSU(179 * MB);  // [1536][512]
    unsigned short* WQKVl = WSU(181 * MB);
    unsigned short* WOh  = WSU(183 * MB);
    unsigned short* WOl  = WSU(183 * MB + 512 * 1024);
    unsigned short* W1h  = WSU(184 * MB);
    unsigned short* W1l  = WSU(186 * MB);
    unsigned short* W2h  = WSU(188 * MB);
    unsigned short* W2l  = WSU(190 * MB);
    float* MTMP = WSF(89 * MB);           // over MQKV (dead after attn)
    float* MY   = WSF(107 * MB);
    unsigned short* MFFh = WSU(125 * MB); // [8960][2048] over MQKV tail + MO
    unsigned short* MFFl = WSU(16 * MB);  // over XL/XR/HN (dead)
    float* MT2  = WSF(71 * MB);           // over SEQ (dead)

    dim3 blk(256);

    // ---- phase 0: preprocessing ----
    hipMemsetAsync(DEGI, 0, NN * 4, stream);
    hipMemsetAsync(CNT, 0, NN * 4, stream);
    hipMemsetAsync(AGG, 0, (size_t)NN * 16 * 4, stream);
    hipMemsetAsync(WE17, 0, (size_t)6 * 17 * D * 4, stream);
    deg_int<<<EE / 256, blk, 0, stream>>>(ei, DEGI);
    scan_deg<<<1, blk, 0, stream>>>(DEGI, OFF);
    csr_fill<<<EE / 256, blk, 0, stream>>>(ei, CNT, OFF, ADJ);
    eagg_acc<<<EE * 16 / 256, blk, 0, stream>>>(edge_attr, ei, AGG);
    ein_build<<<ENL / 256, blk, 0, stream>>>(edge_attr, AGG, DEGI, EIN);
    we17_build<<<dim3(2, 4, 6), blk, 0, stream>>>(e_proj_w, e_proj_b, gat_we, WE17);

    // ---- phase 1: x projection (K=64) ----
    {
        GB g{x, x_proj_w, nullptr, nullptr, x_proj_b, nullptr, nullptr,
             H, nullptr, nullptr, NN, D, 64, 1, 1, 64, 0};
        gemm_f32b<<<dim3(D / 64, NN / 128, 1), blk, 0, stream>>>(g);
    }

    // ---- phase 2: 6x GATv2 (f32, batched z=2) ----
    for (int l = 0; l < 6; ++l) {
        GB g{H, gat_wl + (size_t)l * D * D, gat_wr + (size_t)l * D * D, nullptr,
             gat_bl + l * D, gat_br + l * D, nullptr,
             XL, XR, nullptr, NN, D, D, 1, 1, D, 0};
        gemm_f32b<<<dim3(D / 64, NN / 128, 2), blk, 0, stream>>>(g);
        gat_node<<<NN / 4, blk, 0, stream>>>(XL, XR, EIN, WE17 + (size_t)l * 17 * D,
                                             OFF, ADJ, ei, gat_att + l * D, HN);
        if (l < 5) {
            ln_rows<<<NN / 4, blk, 0, stream>>>(HN, nullptr, gat_bias + l * D,
                gat_ln + (size_t)l * 2 * D, gat_ln + (size_t)l * 2 * D + D, H, NN, 3, 1);
        } else {
            ln_rows<<<NN / 4, blk, 0, stream>>>(HN, nullptr, gat_bias + l * D,
                nullptr, nullptr, H, NN, 0, 1);
        }
    }

    // ---- phase 3: ring encoder (f32) ----
    const int RROWS = RGS * RS;  // 3072
    gather_rows<<<RROWS * D / 256, blk, 0, stream>>>(H, rings_idx, T, RROWS);
    {   // QKV batched z=3
        GB g{T, ring_attn_w + 0 * D * D, ring_attn_w + 1 * D * D, ring_attn_w + 2 * D * D,
             ring_attn_b + 0 * D, ring_attn_b + 1 * D, ring_attn_b + 2 * D,
             RQ, RK, RV, RROWS, D, D, 1, 1, D, 0};
        gemm_f32b<<<dim3(D / 64, RROWS / 128, 3), blk, 0, stream>>>(g);
    }
    ring_attn<<<RGS * 2, blk, 0, stream>>>(RQ, RK, RV, RO);
    {   // O projection: 2-part partials, bias folded in ln
        GB g{RO, ring_attn_w + 3 * D * D, nullptr, nullptr, nullptr, nullptr, nullptr,
             OP, nullptr, nullptr, RROWS, D, D, 0, 2, 256, (long long)RROWS * D};
        gemm_f32b<<<dim3(D / 64, RROWS / 128, 2), blk, 0, stream>>>(g);
    }
    ln_rows<<<RROWS / 4, blk, 0, stream>>>(OP, T, ring_attn_b + 3 * D,
                                           ring_ln, ring_ln + D, RY, RROWS, 2, 2);
    {   // W1: bias + relu epilogue, single-K
        GB g{RY, ring_w1, nullptr, nullptr, ring_b1, nullptr, nullptr,
             RFF, nullptr, nullptr, RROWS, DFF, D, 3, 1, D, 0};
        gemm_f32b<<<dim3(DFF / 64, RROWS / 128, 1), blk, 0, stream>>>(g);
    }
    {   // W2: 4-part partials
        GB g{RFF, ring_w2, nullptr, nullptr, nullptr, nullptr, nullptr,
             W2P, nullptr, nullptr, RROWS, D, DFF, 0, 4, 512, (long long)RROWS * D};
        gemm_f32b<<<dim3(D / 64, RROWS / 128, 4), blk, 0, stream>>>(g);
    }
    ln_rows<<<RROWS / 4, blk, 0, stream>>>(W2P, RY, ring_b2,
                                           ring_ln + 2 * D, ring_ln + 3 * D, RT2, RROWS, 2, 4);
    ring_pick<<<RGS * D / 256, blk, 0, stream>>>(RT2, RVEC);

    // ---- phase 4: mol encoder (MFMA bf16x3 + fused f16 attention) ----
    assemble<<<(NSEQ * D) / 256, blk, 0, stream>>>(H, RVEC, cls_tok, ring_tok, end_tok, SEQ);
    for (int z = 0; z < 3; ++z)
        wsplitT<<<(D * D + 255) / 256, blk, 0, stream>>>(
            mol_attn_w + (size_t)z * D * D, WQKVh + (size_t)z * D * D, WQKVl + (size_t)z * D * D, D, D);
    wsplitT<<<(D * D + 255) / 256, blk, 0, stream>>>(mol_attn_w + 3 * (size_t)D * D, WOh, WOl, D, D);
    wsplitT<<<(D * DFF + 255) / 256, blk, 0, stream>>>(mol_w1, W1h, W1l, D, DFF);
    wsplitT<<<(DFF * D + 255) / 256, blk, 0, stream>>>(mol_w2, W2h, W2l, DFF, D);

    const int N4_512 = MHAT * D / 4;
    float* MQ = MQKV;
    float* MK = MQKV + 512;
    float* MV = MQKV + 1024;
    asplit4<<<(N4_512 + 255) / 256, blk, 0, stream>>>(SEQ, ACTh, ACTl, N4_512);
    // merged QKV: N = 1536 (bias rows 0..2 of mol_attn_b contiguous)
    gemm_split3<<<dim3(1536 / 128, MHAT / 128), blk, 0, stream>>>(
        ACTh, ACTl, WQKVh, WQKVl, mol_attn_b, MQKV, nullptr, nullptr, 1536, D, 1);

    hipFuncSetAttribute(reinterpret_cast<const void*>(mol_attn3),
                        hipFuncAttributeMaxDynamicSharedMemorySize, ATT_SMEM);
    mol_attn3<<<dim3(BMOL * 4, 2), blk, ATT_SMEM, stream>>>(MQ, MK, MV, MO, 1536);

    asplit4<<<(N4_512 + 255) / 256, blk, 0, stream>>>(MO, ACTh, ACTl, N4_512);
    gemm_split3<<<dim3(D / 128, MHAT / 128), blk, 0, stream>>>(
        ACTh, ACTl, WOh, WOl, mol_attn_b + 3 * D, MTMP, nullptr, nullptr, D, D, 1);
    ln_rows<<<(NSEQ + 3) / 4, blk, 0, stream>>>(MTMP, SEQ, nullptr,
                                                mol_ln, mol_ln + D, MY, NSEQ, 2, 1);
    asplit4<<<(N4_512 + 255) / 256, blk, 0, stream>>>(MY, ACTh, ACTl, N4_512);
    gemm_split3<<<dim3(DFF / 128, MHAT / 128), blk, 0, stream>>>(
        ACTh, ACTl, W1h, W1l, mol_b1, nullptr, MFFh, MFFl, DFF, D, 1 | 2 | 4);
    gemm_split3<<<dim3(D / 128, MHAT / 128), blk, 0, stream>>>(
        MFFh, MFFl, W2h, W2l, mol_b2, MT2, nullptr, nullptr, D, DFF, 1);

    float* outf = (float*)d_out;
    ln_rows<<<(NSEQ + 3) / 4, blk, 0, stream>>>(MT2, MY, nullptr,
                                                mol_ln + 2 * D, mol_ln + 3 * D, outf, NSEQ, 2, 1);
    fill_f32<<<(BMOL * 128 + BMOL * 8 + 255) / 256, blk, 0, stream>>>(
        outf + (size_t)NSEQ * D, 1.0f, BMOL * 128 + BMOL * 8);
}